// Round 1
// baseline (749.014 us; speedup 1.0000x reference)
//
#include <hip/hip_runtime.h>

#define DD 512
#define NNODE 100
#define NH 8

typedef __attribute__((ext_vector_type(4))) float f32x4;
typedef __attribute__((ext_vector_type(8))) short s16x8;

__device__ __forceinline__ unsigned short f2bf(float x) {
  union { float f; unsigned int u; } v; v.f = x;
  unsigned int r = v.u + 0x7fffu + ((v.u >> 16) & 1u);
  return (unsigned short)(r >> 16);
}

// Generic C[M,N] = alpha * Aop @ Bop + beta*C, bf16 MFMA, 64x64 tiles.
// A row i base = i*lda + (gidx ? gidx[i]*gmul : 0); element A[base + k].
// transB=1: Bop[k,j] = B[j*ldb + k]; transB=0: Bop[k,j] = B[k*ldb + j].
// Per-z pointer offsets for per-head batched GEMMs.
__global__ __launch_bounds__(256) void gemm_mfma(
    const float* __restrict__ A, const float* __restrict__ B,
    float* __restrict__ C, const int* __restrict__ gidx, int gmul,
    int M, int N, int K, int lda, int ldb, int ldc,
    long aoffz, long boffz, long coffz,
    int transB, float alpha, float beta)
{
  A += (long)blockIdx.z * aoffz;
  B += (long)blockIdx.z * boffz;
  C += (long)blockIdx.z * coffz;
  const int t = threadIdx.x;
  const int m0 = blockIdx.y * 64;
  const int n0 = blockIdx.x * 64;
  __shared__ unsigned short As[64][40];
  __shared__ unsigned short Bs[64][40];
  const int wid = t >> 6, lane = t & 63;
  const int wr = wid >> 1, wc = wid & 1;
  const int r16 = lane & 15, kg = (lane >> 4) * 8;
  f32x4 acc[2][2] = {};
  const int tr = t >> 3, kq = t & 7;  // A/transB staging: (row, k-quad)
  const int bn = t & 63, bk = t >> 6; // notrans B staging: (col, k)

  for (int k0 = 0; k0 < K; k0 += 32) {
    // stage A tile [64 rows][32 k] as bf16
#pragma unroll
    for (int rp = 0; rp < 2; ++rp) {
      const int row = tr + rp * 32;
      const int gi = m0 + row;
      long ab = (long)gi * lda;
      if (gidx) ab += (long)gidx[gi] * gmul;
      const float4 av = *(const float4*)(A + ab + k0 + kq * 4);
      unsigned int p0 = (unsigned)f2bf(av.x) | ((unsigned)f2bf(av.y) << 16);
      unsigned int p1 = (unsigned)f2bf(av.z) | ((unsigned)f2bf(av.w) << 16);
      *(uint2*)(&As[row][kq * 4]) = make_uint2(p0, p1);
    }
    // stage B tile as Bs[col][k]
    if (transB) {
#pragma unroll
      for (int rp = 0; rp < 2; ++rp) {
        const int row = tr + rp * 32;
        const float4 bv = *(const float4*)(B + (long)(n0 + row) * ldb + k0 + kq * 4);
        unsigned int p0 = (unsigned)f2bf(bv.x) | ((unsigned)f2bf(bv.y) << 16);
        unsigned int p1 = (unsigned)f2bf(bv.z) | ((unsigned)f2bf(bv.w) << 16);
        *(uint2*)(&Bs[row][kq * 4]) = make_uint2(p0, p1);
      }
    } else {
#pragma unroll
      for (int pp = 0; pp < 8; ++pp) {
        const int k = bk + pp * 4;
        Bs[bn][k] = f2bf(B[(long)(k0 + k) * ldb + n0 + bn]);
      }
    }
    __syncthreads();
    s16x8 a0 = *(const s16x8*)(&As[wr * 32 + r16][kg]);
    s16x8 a1 = *(const s16x8*)(&As[wr * 32 + 16 + r16][kg]);
    s16x8 b0 = *(const s16x8*)(&Bs[wc * 32 + r16][kg]);
    s16x8 b1 = *(const s16x8*)(&Bs[wc * 32 + 16 + r16][kg]);
    acc[0][0] = __builtin_amdgcn_mfma_f32_16x16x32_bf16(a0, b0, acc[0][0], 0, 0, 0);
    acc[0][1] = __builtin_amdgcn_mfma_f32_16x16x32_bf16(a0, b1, acc[0][1], 0, 0, 0);
    acc[1][0] = __builtin_amdgcn_mfma_f32_16x16x32_bf16(a1, b0, acc[1][0], 0, 0, 0);
    acc[1][1] = __builtin_amdgcn_mfma_f32_16x16x32_bf16(a1, b1, acc[1][1], 0, 0, 0);
    __syncthreads();
  }
#pragma unroll
  for (int si = 0; si < 2; ++si)
#pragma unroll
    for (int sj = 0; sj < 2; ++sj)
#pragma unroll
      for (int r = 0; r < 4; ++r) {
        const int row = m0 + wr * 32 + si * 16 + (lane >> 4) * 4 + r;
        const int col = n0 + wc * 32 + sj * 16 + r16;
        const long ci = (long)row * ldc + col;
        float v = alpha * acc[si][sj][r];
        if (beta != 0.f) v = fmaf(beta, C[ci], v);
        C[ci] = v;
      }
}

// Per-batch attention: scores[h,n] = qk[h,:]·node[n,:], online softmax over n,
// ctx[h,:] = sum_n attn[h,n]*node[n,:].  One block per b, 256 thr.
// Thread (h = t>>5, c = t&31) owns k-slices {c+32i} and ctx[h][c+32i].
__global__ __launch_bounds__(256) void attn_ctx_kernel(
    const float* __restrict__ node, const float* __restrict__ qk,
    float* __restrict__ ctx)
{
  const int b = blockIdx.x;
  const int t = threadIdx.x;
  const int h = t >> 5;
  const int c = t & 31;
  const float* nb = node + (long)b * (NNODE * DD);
  const float* qb = qk + (long)b * (NH * DD) + h * DD + c;
  float qr[16], cx[16];
#pragma unroll
  for (int i = 0; i < 16; ++i) { qr[i] = qb[i * 32]; cx[i] = 0.f; }
  float m = -3.0e38f, l = 0.f;
  __shared__ float nl[16][DD];

  for (int c0 = 0; c0 < NNODE; c0 += 16) {
    const int rows = (NNODE - c0 < 16) ? (NNODE - c0) : 16;
    __syncthreads();
    const float4* src = (const float4*)(nb + (long)c0 * DD);
    float4* dst = (float4*)(&nl[0][0]);
    const int nf4 = rows * (DD / 4);
    for (int idx = t; idx < nf4; idx += 256) dst[idx] = src[idx];
    float4 z4; z4.x = z4.y = z4.z = z4.w = 0.f;
    for (int idx = nf4 + t; idx < 16 * (DD / 4); idx += 256) dst[idx] = z4;
    __syncthreads();

    float s[16], p[16];
    float cm = -3.0e38f;
#pragma unroll
    for (int n = 0; n < 16; ++n) {
      float acc = 0.f;
#pragma unroll
      for (int i = 0; i < 16; ++i) acc = fmaf(nl[n][c + 32 * i], qr[i], acc);
#pragma unroll
      for (int off = 1; off < 32; off <<= 1) acc += __shfl_xor(acc, off);
      s[n] = (c0 + n < NNODE) ? acc : -3.0e38f;
      cm = fmaxf(cm, s[n]);
    }
    const float mn = fmaxf(m, cm);
    const float rsc = __expf(m - mn);
    float ps = 0.f;
#pragma unroll
    for (int n = 0; n < 16; ++n) { p[n] = __expf(s[n] - mn); ps += p[n]; }
    l = l * rsc + ps;
    m = mn;
#pragma unroll
    for (int i = 0; i < 16; ++i) cx[i] *= rsc;
#pragma unroll
    for (int n = 0; n < 16; ++n) {
      const float pn = p[n];
#pragma unroll
      for (int i = 0; i < 16; ++i) cx[i] = fmaf(pn, nl[n][c + 32 * i], cx[i]);
    }
  }
  const float inv = 1.f / l;
  float* cb = ctx + (long)b * (NH * DD) + h * DD + c;
#pragma unroll
  for (int i = 0; i < 16; ++i) cb[i * 32] = cx[i] * inv;
}

// Final pass: logit[n] = 10*tanh(node[n,:]·qk2) - mask*1e9; log_softmax over n.
__global__ __launch_bounds__(256) void logits_kernel(
    const float* __restrict__ node, const float* __restrict__ qk2,
    const int* __restrict__ mask, float* __restrict__ out)
{
  const int b = blockIdx.x;
  const int t = threadIdx.x;
  const int lane = t & 63;
  const int w = t >> 6;
  const float* nb = node + (long)b * (NNODE * DD);
  const float* q2 = qk2 + (long)b * DD + lane;
  float qr[8];
#pragma unroll
  for (int i = 0; i < 8; ++i) qr[i] = q2[i * 64];
  __shared__ float sl[128];
  for (int n = w; n < NNODE; n += 4) {
    const float* row = nb + (long)n * DD + lane;
    float acc = 0.f;
#pragma unroll
    for (int i = 0; i < 8; ++i) acc = fmaf(row[i * 64], qr[i], acc);
#pragma unroll
    for (int off = 1; off < 64; off <<= 1) acc += __shfl_xor(acc, off);
    if (lane == 0) {
      float lg = 10.f * tanhf(acc);
      lg -= (float)mask[b * NNODE + n] * 1e9f;
      sl[n] = lg;
    }
  }
  __syncthreads();
  if (w == 0) {
    const float v0 = (lane < NNODE) ? sl[lane] : -3.0e38f;
    const float v1 = (lane + 64 < NNODE) ? sl[lane + 64] : -3.0e38f;
    float mx = fmaxf(v0, v1);
#pragma unroll
    for (int off = 1; off < 64; off <<= 1) mx = fmaxf(mx, __shfl_xor(mx, off));
    float e = 0.f;
    if (lane < NNODE) e += __expf(v0 - mx);
    if (lane + 64 < NNODE) e += __expf(v1 - mx);
#pragma unroll
    for (int off = 1; off < 64; off <<= 1) e += __shfl_xor(e, off);
    const float lse = mx + __logf(e);
    float* ob = out + (long)b * NNODE;
    if (lane < NNODE) ob[lane] = v0 - lse;
    if (lane + 64 < NNODE) ob[lane + 64] = v1 - lse;
  }
}

extern "C" void kernel_launch(void* const* d_in, const int* in_sizes, int n_in,
                              void* d_out, int out_size, void* d_ws, size_t ws_size,
                              hipStream_t stream) {
  const float* node     = (const float*)d_in[0];
  const float* graph    = (const float*)d_in[1];
  const int*   tidx     = (const int*)d_in[2];
  const int*   mask     = (const int*)d_in[3];
  const float* W_target = (const float*)d_in[4];
  const float* W_global = (const float*)d_in[5];
  const float* W_K1     = (const float*)d_in[6];
  const float* W_K2     = (const float*)d_in[7];
  const float* W_Q      = (const float*)d_in[8];
  const float* W_V      = (const float*)d_in[9];
  const float* Wq_mha   = (const float*)d_in[10];
  const float* Wk_mha   = (const float*)d_in[11];
  const float* Wv_mha   = (const float*)d_in[12];
  const float* Wo_mha   = (const float*)d_in[13];
  float* out = (float*)d_out;

  float* A1   = (float*)d_ws;            // 512*512 each
  float* A2   = A1 + 262144;
  float* Wkc  = A2 + 262144;
  float* Wvc  = Wkc + 262144;
  float* Woq  = Wvc + 262144;
  float* qbuf = Woq + 262144;            // 2048*512
  float* qkv  = qbuf + 2048 * 512;       // 2048*4096
  float* ctxb = qkv + 2048 * 4096;       // 2048*4096
  float* preo = qkv;                     // alias: qkv dead after attn
  float* query = qkv + 1048576;
  float* qk2  = qkv + 2097152;

  dim3 blk(256);
  const float SH = 0.125f;               // 1/sqrt(64)
  const float SD = 0.044194173824f;      // 1/sqrt(512)

  // weight folds: A1=Wq@Wt, A2=Wq@Wg, Wkc=sh*(Wk@WK1), Wvc=Wv@WV, Woq=WQ@Wo
  gemm_mfma<<<dim3(8,8,1), blk, 0, stream>>>(Wq_mha, W_target, A1, nullptr, 0,
      512,512,512, 512,512,512, 0,0,0, 0, 1.f, 0.f);
  gemm_mfma<<<dim3(8,8,1), blk, 0, stream>>>(Wq_mha, W_global, A2, nullptr, 0,
      512,512,512, 512,512,512, 0,0,0, 0, 1.f, 0.f);
  gemm_mfma<<<dim3(8,8,1), blk, 0, stream>>>(Wk_mha, W_K1, Wkc, nullptr, 0,
      512,512,512, 512,512,512, 0,0,0, 0, SH, 0.f);
  gemm_mfma<<<dim3(8,8,1), blk, 0, stream>>>(Wv_mha, W_V, Wvc, nullptr, 0,
      512,512,512, 512,512,512, 0,0,0, 0, 1.f, 0.f);
  gemm_mfma<<<dim3(8,8,1), blk, 0, stream>>>(W_Q, Wo_mha, Woq, nullptr, 0,
      512,512,512, 512,512,512, 0,0,0, 0, 1.f, 0.f);
  // q = tgt @ A1^T + graph @ A2^T   (tgt gathered from node via target_idx)
  gemm_mfma<<<dim3(8,32,1), blk, 0, stream>>>(node, A1, qbuf, tidx, DD,
      2048,512,512, NNODE*DD,512,512, 0,0,0, 1, 1.f, 0.f);
  gemm_mfma<<<dim3(8,32,1), blk, 0, stream>>>(graph, A2, qbuf, nullptr, 0,
      2048,512,512, 512,512,512, 0,0,0, 1, 1.f, 1.f);
  // qk[b,h,:] = q[b, head h] @ Wkc[head h rows]   (K=64 per head)
  gemm_mfma<<<dim3(8,32,8), blk, 0, stream>>>(qbuf, Wkc, qkv, nullptr, 0,
      2048,512,64, 512,512,4096, 64, 32768, 512, 0, 1.f, 0.f);
  // attention context (streams node once, online softmax)
  attn_ctx_kernel<<<dim3(2048), blk, 0, stream>>>(node, qkv, ctxb);
  // pre_o[b, head h] = ctx[b,h,:] @ Wvc[head h rows]^T
  gemm_mfma<<<dim3(1,32,8), blk, 0, stream>>>(ctxb, Wvc, preo, nullptr, 0,
      2048,64,512, 4096,512,512, 512, 32768, 64, 1, 1.f, 0.f);
  // query = pre_o @ Woq^T
  gemm_mfma<<<dim3(8,32,1), blk, 0, stream>>>(preo, Woq, query, nullptr, 0,
      2048,512,512, 512,512,512, 0,0,0, 1, 1.f, 0.f);
  // qk2 = (1/sqrt(D)) * query @ W_K2
  gemm_mfma<<<dim3(8,32,1), blk, 0, stream>>>(query, W_K2, qk2, nullptr, 0,
      2048,512,512, 512,512,512, 0,0,0, 0, SD, 0.f);
  // logits + masked log_softmax (streams node once)
  logits_kernel<<<dim3(2048), blk, 0, stream>>>(node, qk2, mask, out);

  (void)in_sizes; (void)n_in; (void)out_size; (void)ws_size;
}

// Round 2
// 565.921 us; speedup vs baseline: 1.3235x; 1.3235x over previous
//
#include <hip/hip_runtime.h>

#define DD 512
#define NNODE 100
#define NH 8
#define NPAD 112

typedef __attribute__((ext_vector_type(4))) float f32x4;
typedef __attribute__((ext_vector_type(8))) short s16x8;

__device__ __forceinline__ unsigned short f2bf(float x) {
  union { float f; unsigned int u; } v; v.f = x;
  unsigned int r = v.u + 0x7fffu + ((v.u >> 16) & 1u);
  return (unsigned short)(r >> 16);
}

// Generic C[M,N] = alpha * Aop @ Bop + beta*C, bf16 MFMA, 64x64 tiles.
__global__ __launch_bounds__(256) void gemm_mfma(
    const float* __restrict__ A, const float* __restrict__ B,
    float* __restrict__ C, const int* __restrict__ gidx, int gmul,
    int M, int N, int K, int lda, int ldb, int ldc,
    long aoffz, long boffz, long coffz,
    int transB, float alpha, float beta)
{
  A += (long)blockIdx.z * aoffz;
  B += (long)blockIdx.z * boffz;
  C += (long)blockIdx.z * coffz;
  const int t = threadIdx.x;
  const int m0 = blockIdx.y * 64;
  const int n0 = blockIdx.x * 64;
  __shared__ unsigned short As[64][40];
  __shared__ unsigned short Bs[64][40];
  const int wid = t >> 6, lane = t & 63;
  const int wr = wid >> 1, wc = wid & 1;
  const int r16 = lane & 15, kg = (lane >> 4) * 8;
  f32x4 acc[2][2] = {};
  const int tr = t >> 3, kq = t & 7;
  const int bn = t & 63, bk = t >> 6;

  for (int k0 = 0; k0 < K; k0 += 32) {
#pragma unroll
    for (int rp = 0; rp < 2; ++rp) {
      const int row = tr + rp * 32;
      const int gi = m0 + row;
      long ab = (long)gi * lda;
      if (gidx) ab += (long)gidx[gi] * gmul;
      const float4 av = *(const float4*)(A + ab + k0 + kq * 4);
      unsigned int p0 = (unsigned)f2bf(av.x) | ((unsigned)f2bf(av.y) << 16);
      unsigned int p1 = (unsigned)f2bf(av.z) | ((unsigned)f2bf(av.w) << 16);
      *(uint2*)(&As[row][kq * 4]) = make_uint2(p0, p1);
    }
    if (transB) {
#pragma unroll
      for (int rp = 0; rp < 2; ++rp) {
        const int row = tr + rp * 32;
        const float4 bv = *(const float4*)(B + (long)(n0 + row) * ldb + k0 + kq * 4);
        unsigned int p0 = (unsigned)f2bf(bv.x) | ((unsigned)f2bf(bv.y) << 16);
        unsigned int p1 = (unsigned)f2bf(bv.z) | ((unsigned)f2bf(bv.w) << 16);
        *(uint2*)(&Bs[row][kq * 4]) = make_uint2(p0, p1);
      }
    } else {
#pragma unroll
      for (int pp = 0; pp < 8; ++pp) {
        const int k = bk + pp * 4;
        Bs[bn][k] = f2bf(B[(long)(k0 + k) * ldb + n0 + bn]);
      }
    }
    __syncthreads();
    s16x8 a0 = *(const s16x8*)(&As[wr * 32 + r16][kg]);
    s16x8 a1 = *(const s16x8*)(&As[wr * 32 + 16 + r16][kg]);
    s16x8 b0 = *(const s16x8*)(&Bs[wc * 32 + r16][kg]);
    s16x8 b1 = *(const s16x8*)(&Bs[wc * 32 + 16 + r16][kg]);
    acc[0][0] = __builtin_amdgcn_mfma_f32_16x16x32_bf16(a0, b0, acc[0][0], 0, 0, 0);
    acc[0][1] = __builtin_amdgcn_mfma_f32_16x16x32_bf16(a0, b1, acc[0][1], 0, 0, 0);
    acc[1][0] = __builtin_amdgcn_mfma_f32_16x16x32_bf16(a1, b0, acc[1][0], 0, 0, 0);
    acc[1][1] = __builtin_amdgcn_mfma_f32_16x16x32_bf16(a1, b1, acc[1][1], 0, 0, 0);
    __syncthreads();
  }
#pragma unroll
  for (int si = 0; si < 2; ++si)
#pragma unroll
    for (int sj = 0; sj < 2; ++sj)
#pragma unroll
      for (int r = 0; r < 4; ++r) {
        const int row = m0 + wr * 32 + si * 16 + (lane >> 4) * 4 + r;
        const int col = n0 + wc * 32 + sj * 16 + r16;
        const long ci = (long)row * ldc + col;
        float v = alpha * acc[si][sj][r];
        if (beta != 0.f) v = fmaf(beta, C[ci], v);
        C[ci] = v;
      }
}

// S[b, n-tile, h] = node[b,n,:] . q[b,h,:] via MFMA, direct-from-global.
// grid (4, B), block 128 (2 waves); wave handles one 16-node tile.
// q layout [b][nh][512]; S layout [b][NPAD][nh].
__global__ __launch_bounds__(128) void scores_kernel(
    const float* __restrict__ node, const float* __restrict__ q,
    float* __restrict__ S, int nh)
{
  const int b = blockIdx.y;
  const int t = threadIdx.x;
  const int w = t >> 6, lane = t & 63;
  const int tile = blockIdx.x * 2 + w;
  const int n0 = tile * 16;
  const int r16 = lane & 15;
  const int kg = (lane >> 4) * 8;
  const int arow = min(n0 + r16, NNODE - 1);   // clamp: dup rows, masked at store
  const int hb = min(r16, nh - 1);             // clamp: dup heads, masked at store
  const float* ap = node + ((long)b * NNODE + arow) * DD + kg;
  const float* bp = q + ((long)b * nh + hb) * DD + kg;
  f32x4 acc = {0.f, 0.f, 0.f, 0.f};
  for (int s = 0; s < 16; ++s) {
    const float4 a0 = *(const float4*)(ap + s * 32);
    const float4 a1 = *(const float4*)(ap + s * 32 + 4);
    const float4 b0 = *(const float4*)(bp + s * 32);
    const float4 b1 = *(const float4*)(bp + s * 32 + 4);
    s16x8 af, bf;
    af[0] = (short)f2bf(a0.x); af[1] = (short)f2bf(a0.y);
    af[2] = (short)f2bf(a0.z); af[3] = (short)f2bf(a0.w);
    af[4] = (short)f2bf(a1.x); af[5] = (short)f2bf(a1.y);
    af[6] = (short)f2bf(a1.z); af[7] = (short)f2bf(a1.w);
    bf[0] = (short)f2bf(b0.x); bf[1] = (short)f2bf(b0.y);
    bf[2] = (short)f2bf(b0.z); bf[3] = (short)f2bf(b0.w);
    bf[4] = (short)f2bf(b1.x); bf[5] = (short)f2bf(b1.y);
    bf[6] = (short)f2bf(b1.z); bf[7] = (short)f2bf(b1.w);
    acc = __builtin_amdgcn_mfma_f32_16x16x32_bf16(af, bf, acc, 0, 0, 0);
  }
  if (r16 < nh) {
#pragma unroll
    for (int r = 0; r < 4; ++r) {
      const int n = n0 + (lane >> 4) * 4 + r;
      if (n < NPAD) S[((long)b * NPAD + n) * nh + r16] = acc[r];
    }
  }
}

// Per-batch softmax over n for each head; writes transposed probs Pt[b][n][h].
__global__ __launch_bounds__(64) void softmax_kernel(
    const float* __restrict__ S, float* __restrict__ Pt)
{
  const int b = blockIdx.x;
  const int lane = threadIdx.x;
  const int h = lane >> 3, sub = lane & 7;
  float v[13];
  float m = -3.0e38f;
#pragma unroll
  for (int k = 0; k < 13; ++k) {
    const int n = sub + 8 * k;
    v[k] = (n < NNODE) ? S[((long)b * NPAD + n) * NH + h] : -3.0e38f;
    m = fmaxf(m, v[k]);
  }
  m = fmaxf(m, __shfl_xor(m, 1));
  m = fmaxf(m, __shfl_xor(m, 2));
  m = fmaxf(m, __shfl_xor(m, 4));
  float e[13], sum = 0.f;
#pragma unroll
  for (int k = 0; k < 13; ++k) {
    const int n = sub + 8 * k;
    e[k] = (n < NNODE) ? __expf(v[k] - m) : 0.f;
    sum += e[k];
  }
  sum += __shfl_xor(sum, 1);
  sum += __shfl_xor(sum, 2);
  sum += __shfl_xor(sum, 4);
  const float inv = 1.f / sum;
#pragma unroll
  for (int k = 0; k < 13; ++k) {
    const int n = sub + 8 * k;
    if (n < NNODE) Pt[((long)b * NPAD + n) * NH + h] = e[k] * inv;
  }
  // zero-pad rows 100..111 so ctx can run unguarded
  for (int i = lane; i < (NPAD - NNODE) * NH; i += 64)
    Pt[((long)b * NPAD + NNODE) * NH + i] = 0.f;
}

// ctx[b,h,d] = sum_n Pt[b,n,h] * node[b,n,d].  Pure streaming: thread owns a
// d-float4 for all 8 heads; node read coalesced from global exactly once.
__global__ __launch_bounds__(128) void ctx_kernel(
    const float* __restrict__ node, const float* __restrict__ Pt,
    float* __restrict__ ctx)
{
  const int b = blockIdx.x;
  const int t = threadIdx.x;
  const int d0 = t * 4;
  __shared__ float shP[NPAD * NH];
  for (int i = t; i < NPAD * NH; i += 128) shP[i] = Pt[(long)b * NPAD * NH + i];
  __syncthreads();
  f32x4 cx[NH] = {};
  const float* nb = node + (long)b * NNODE * DD + d0;
#pragma unroll 2
  for (int n = 0; n < NNODE; ++n) {
    const f32x4 nv = *(const f32x4*)(nb + (long)n * DD);
    const f32x4 p0 = *(const f32x4*)(&shP[n * NH]);
    const f32x4 p1 = *(const f32x4*)(&shP[n * NH + 4]);
    cx[0] += p0[0] * nv; cx[1] += p0[1] * nv;
    cx[2] += p0[2] * nv; cx[3] += p0[3] * nv;
    cx[4] += p1[0] * nv; cx[5] += p1[1] * nv;
    cx[6] += p1[2] * nv; cx[7] += p1[3] * nv;
  }
  float* cb = ctx + (long)b * NH * DD + d0;
#pragma unroll
  for (int h = 0; h < NH; ++h) *(f32x4*)(cb + h * DD) = cx[h];
}

// Final: lg[n] = 10*tanh(S2[n]) - mask*1e9; out = log_softmax(lg).
__global__ __launch_bounds__(64) void logits_fin(
    const float* __restrict__ S2, const int* __restrict__ mask,
    float* __restrict__ out)
{
  const int b = blockIdx.x;
  const int lane = threadIdx.x;
  float v0 = -3.0e38f, v1 = -3.0e38f;
  if (lane < NNODE)
    v0 = 10.f * tanhf(S2[(long)b * NPAD + lane]) - (float)mask[b * NNODE + lane] * 1e9f;
  if (lane + 64 < NNODE)
    v1 = 10.f * tanhf(S2[(long)b * NPAD + lane + 64]) - (float)mask[b * NNODE + lane + 64] * 1e9f;
  float mx = fmaxf(v0, v1);
#pragma unroll
  for (int off = 1; off < 64; off <<= 1) mx = fmaxf(mx, __shfl_xor(mx, off));
  float e = 0.f;
  if (lane < NNODE) e += __expf(v0 - mx);
  if (lane + 64 < NNODE) e += __expf(v1 - mx);
#pragma unroll
  for (int off = 1; off < 64; off <<= 1) e += __shfl_xor(e, off);
  const float lse = mx + __logf(e);
  float* ob = out + (long)b * NNODE;
  if (lane < NNODE) ob[lane] = v0 - lse;
  if (lane + 64 < NNODE) ob[lane + 64] = v1 - lse;
}

extern "C" void kernel_launch(void* const* d_in, const int* in_sizes, int n_in,
                              void* d_out, int out_size, void* d_ws, size_t ws_size,
                              hipStream_t stream) {
  const float* node     = (const float*)d_in[0];
  const float* graph    = (const float*)d_in[1];
  const int*   tidx     = (const int*)d_in[2];
  const int*   mask     = (const int*)d_in[3];
  const float* W_target = (const float*)d_in[4];
  const float* W_global = (const float*)d_in[5];
  const float* W_K1     = (const float*)d_in[6];
  const float* W_K2     = (const float*)d_in[7];
  const float* W_Q      = (const float*)d_in[8];
  const float* W_V      = (const float*)d_in[9];
  const float* Wq_mha   = (const float*)d_in[10];
  const float* Wk_mha   = (const float*)d_in[11];
  const float* Wv_mha   = (const float*)d_in[12];
  const float* Wo_mha   = (const float*)d_in[13];
  float* out = (float*)d_out;

  // workspace layout (floats) — peak 76.5 MB, same as validated round-1 layout
  float* A1   = (float*)d_ws;            // 262144 each
  float* A2   = A1 + 262144;
  float* Wkc  = A2 + 262144;
  float* Wvc  = Wkc + 262144;
  float* Woq  = Wvc + 262144;
  float* qbuf = Woq + 262144;            // 2048*512   (dead after qk GEMM)
  float* qkv  = qbuf + 2048 * 512;       // 2048*4096  (qk; dead after scores)
  float* ctxb = qkv + 2048 * 4096;       // 2048*4096
  // aliases
  float* Sbuf = ctxb;                    // 2048*112*8  (dead before ctx writes)
  float* Ptb  = qkv;                     // 2048*112*8  (qk dead by then)
  float* preo = qkv + 2097152;           // 2048*512
  float* query = qkv + 4194304;          // 2048*512
  float* qk2  = qkv + 6291456;           // 2048*512
  float* S2   = qbuf;                    // 2048*112    (qbuf dead by then)

  dim3 blk(256);
  const float SH = 0.125f;               // 1/sqrt(64)
  const float SD = 0.044194173824f;      // 1/sqrt(512)

  // weight folds
  gemm_mfma<<<dim3(8,8,1), blk, 0, stream>>>(Wq_mha, W_target, A1, nullptr, 0,
      512,512,512, 512,512,512, 0,0,0, 0, 1.f, 0.f);
  gemm_mfma<<<dim3(8,8,1), blk, 0, stream>>>(Wq_mha, W_global, A2, nullptr, 0,
      512,512,512, 512,512,512, 0,0,0, 0, 1.f, 0.f);
  gemm_mfma<<<dim3(8,8,1), blk, 0, stream>>>(Wk_mha, W_K1, Wkc, nullptr, 0,
      512,512,512, 512,512,512, 0,0,0, 0, SH, 0.f);
  gemm_mfma<<<dim3(8,8,1), blk, 0, stream>>>(Wv_mha, W_V, Wvc, nullptr, 0,
      512,512,512, 512,512,512, 0,0,0, 0, 1.f, 0.f);
  gemm_mfma<<<dim3(8,8,1), blk, 0, stream>>>(W_Q, Wo_mha, Woq, nullptr, 0,
      512,512,512, 512,512,512, 0,0,0, 0, 1.f, 0.f);
  // q = tgt @ A1^T + graph @ A2^T
  gemm_mfma<<<dim3(8,32,1), blk, 0, stream>>>(node, A1, qbuf, tidx, DD,
      2048,512,512, NNODE*DD,512,512, 0,0,0, 1, 1.f, 0.f);
  gemm_mfma<<<dim3(8,32,1), blk, 0, stream>>>(graph, A2, qbuf, nullptr, 0,
      2048,512,512, 512,512,512, 0,0,0, 1, 1.f, 1.f);
  // qk[b,h,:] = q[b, head h] @ Wkc[head h rows]
  gemm_mfma<<<dim3(8,32,8), blk, 0, stream>>>(qbuf, Wkc, qkv, nullptr, 0,
      2048,512,64, 512,512,4096, 64, 32768, 512, 0, 1.f, 0.f);
  // attention: scores -> softmax -> ctx (node streamed twice, fully parallel)
  scores_kernel<<<dim3(4,2048), dim3(128), 0, stream>>>(node, qkv, Sbuf, NH);
  softmax_kernel<<<dim3(2048), dim3(64), 0, stream>>>(Sbuf, Ptb);
  ctx_kernel<<<dim3(2048), dim3(128), 0, stream>>>(node, Ptb, ctxb);
  // pre_o[b, head h] = ctx[b,h,:] @ Wvc[head h rows]^T
  gemm_mfma<<<dim3(1,32,8), blk, 0, stream>>>(ctxb, Wvc, preo, nullptr, 0,
      2048,64,512, 4096,512,512, 512, 32768, 64, 1, 1.f, 0.f);
  // query = pre_o @ Woq^T
  gemm_mfma<<<dim3(8,32,1), blk, 0, stream>>>(preo, Woq, query, nullptr, 0,
      2048,512,512, 512,512,512, 0,0,0, 1, 1.f, 0.f);
  // qk2 = (1/sqrt(D)) * query @ W_K2
  gemm_mfma<<<dim3(8,32,1), blk, 0, stream>>>(query, W_K2, qk2, nullptr, 0,
      2048,512,512, 512,512,512, 0,0,0, 0, SD, 0.f);
  // logit dots + finish
  scores_kernel<<<dim3(4,2048), dim3(128), 0, stream>>>(node, qk2, S2, 1);
  logits_fin<<<dim3(2048), dim3(64), 0, stream>>>(S2, mask, out);

  (void)in_sizes; (void)n_in; (void)out_size; (void)ws_size;
}

// Round 3
// 413.164 us; speedup vs baseline: 1.8129x; 1.3697x over previous
//
#include <hip/hip_runtime.h>

#define DD 512
#define NNODE 100
#define NH 8
#define NPAD 112

typedef __attribute__((ext_vector_type(4))) float f32x4;
typedef __attribute__((ext_vector_type(8))) short s16x8;

__device__ __forceinline__ unsigned short f2bf(float x) {
  union { float f; unsigned int u; } v; v.f = x;
  unsigned int r = v.u + 0x7fffu + ((v.u >> 16) & 1u);
  return (unsigned short)(r >> 16);
}
__device__ __forceinline__ float bf2f(unsigned short u) {
  union { unsigned int u; float f; } v; v.u = ((unsigned int)u) << 16;
  return v.f;
}

// ---- shared GEMM core: 64x64 tile, 4 waves, bf16 MFMA 16x16x32 ----
__device__ __forceinline__ void gemm_accum(
    f32x4 acc[2][2], const float* __restrict__ A, const float* __restrict__ B,
    const int* __restrict__ gidx, int gmul, int K, int lda, int ldb,
    int transB, int m0, int n0,
    unsigned short (*As)[40], unsigned short (*Bs)[40])
{
  const int t = threadIdx.x;
  const int wid = t >> 6, lane = t & 63;
  const int wr = wid >> 1, wc = wid & 1;
  const int r16 = lane & 15, kg = (lane >> 4) * 8;
  const int tr = t >> 3, kq = t & 7;
  const int bn = t & 63, bk = t >> 6;

  for (int k0 = 0; k0 < K; k0 += 32) {
#pragma unroll
    for (int rp = 0; rp < 2; ++rp) {
      const int row = tr + rp * 32;
      const int gi = m0 + row;
      long ab = (long)gi * lda;
      if (gidx) ab += (long)gidx[gi] * gmul;
      const float4 av = *(const float4*)(A + ab + k0 + kq * 4);
      unsigned int p0 = (unsigned)f2bf(av.x) | ((unsigned)f2bf(av.y) << 16);
      unsigned int p1 = (unsigned)f2bf(av.z) | ((unsigned)f2bf(av.w) << 16);
      *(uint2*)(&As[row][kq * 4]) = make_uint2(p0, p1);
    }
    if (transB) {
#pragma unroll
      for (int rp = 0; rp < 2; ++rp) {
        const int row = tr + rp * 32;
        const float4 bv = *(const float4*)(B + (long)(n0 + row) * ldb + k0 + kq * 4);
        unsigned int p0 = (unsigned)f2bf(bv.x) | ((unsigned)f2bf(bv.y) << 16);
        unsigned int p1 = (unsigned)f2bf(bv.z) | ((unsigned)f2bf(bv.w) << 16);
        *(uint2*)(&Bs[row][kq * 4]) = make_uint2(p0, p1);
      }
    } else {
#pragma unroll
      for (int pp = 0; pp < 8; ++pp) {
        const int k = bk + pp * 4;
        Bs[bn][k] = f2bf(B[(long)(k0 + k) * ldb + n0 + bn]);
      }
    }
    __syncthreads();
    s16x8 a0 = *(const s16x8*)(&As[wr * 32 + r16][kg]);
    s16x8 a1 = *(const s16x8*)(&As[wr * 32 + 16 + r16][kg]);
    s16x8 b0 = *(const s16x8*)(&Bs[wc * 32 + r16][kg]);
    s16x8 b1 = *(const s16x8*)(&Bs[wc * 32 + 16 + r16][kg]);
    acc[0][0] = __builtin_amdgcn_mfma_f32_16x16x32_bf16(a0, b0, acc[0][0], 0, 0, 0);
    acc[0][1] = __builtin_amdgcn_mfma_f32_16x16x32_bf16(a0, b1, acc[0][1], 0, 0, 0);
    acc[1][0] = __builtin_amdgcn_mfma_f32_16x16x32_bf16(a1, b0, acc[1][0], 0, 0, 0);
    acc[1][1] = __builtin_amdgcn_mfma_f32_16x16x32_bf16(a1, b1, acc[1][1], 0, 0, 0);
    __syncthreads();
  }
}

__device__ __forceinline__ void gemm_epilogue(
    f32x4 acc[2][2], void* Cv, int ldc, float alpha, float beta, int obf16,
    int m0, int n0)
{
  const int t = threadIdx.x;
  const int wid = t >> 6, lane = t & 63;
  const int wr = wid >> 1, wc = wid & 1;
  const int r16 = lane & 15;
#pragma unroll
  for (int si = 0; si < 2; ++si)
#pragma unroll
    for (int sj = 0; sj < 2; ++sj)
#pragma unroll
      for (int r = 0; r < 4; ++r) {
        const int row = m0 + wr * 32 + si * 16 + (lane >> 4) * 4 + r;
        const int col = n0 + wc * 32 + sj * 16 + r16;
        const long ci = (long)row * ldc + col;
        float v = alpha * acc[si][sj][r];
        if (obf16) {
          ((unsigned short*)Cv)[ci] = f2bf(v);
        } else {
          float* C = (float*)Cv;
          if (beta != 0.f) v = fmaf(beta, C[ci], v);
          C[ci] = v;
        }
      }
}

__global__ __launch_bounds__(256) void gemm_mfma(
    const float* __restrict__ A, const float* __restrict__ B, void* Cv,
    int K, int lda, int ldb, int ldc,
    long aoffz, long boffz, long coffz,
    int transB, float alpha, float beta, int obf16)
{
  __shared__ unsigned short As[64][40];
  __shared__ unsigned short Bs[64][40];
  A += (long)blockIdx.z * aoffz;
  B += (long)blockIdx.z * boffz;
  f32x4 acc[2][2] = {};
  gemm_accum(acc, A, B, nullptr, 0, K, lda, ldb, transB,
             blockIdx.y * 64, blockIdx.x * 64, As, Bs);
  void* Cz = obf16 ? (void*)((unsigned short*)Cv + (long)blockIdx.z * coffz)
                   : (void*)((float*)Cv + (long)blockIdx.z * coffz);
  gemm_epilogue(acc, Cz, ldc, alpha, beta, obf16, blockIdx.y * 64, blockIdx.x * 64);
}

struct Fold5Args {
  const float* A[5]; const float* B[5]; float* C[5]; float al[5];
};

// 5 independent 512^3 weight folds in one launch (grid.z selects)
__global__ __launch_bounds__(256) void fold5_kernel(Fold5Args fa) {
  __shared__ unsigned short As[64][40];
  __shared__ unsigned short Bs[64][40];
  const int z = blockIdx.z;
  f32x4 acc[2][2] = {};
  gemm_accum(acc, fa.A[z], fa.B[z], nullptr, 0, 512, 512, 512, 0,
             blockIdx.y * 64, blockIdx.x * 64, As, Bs);
  gemm_epilogue(acc, fa.C[z], 512, fa.al[z], 0.f, 0, blockIdx.y * 64, blockIdx.x * 64);
}

// qbuf = tgt @ A1^T + graph @ A2^T, both K=512 passes accumulated in registers
__global__ __launch_bounds__(256) void qbuf_kernel(
    const float* __restrict__ node, const float* __restrict__ graph,
    const int* __restrict__ tidx, const float* __restrict__ A1,
    const float* __restrict__ A2, float* __restrict__ C)
{
  __shared__ unsigned short As[64][40];
  __shared__ unsigned short Bs[64][40];
  f32x4 acc[2][2] = {};
  gemm_accum(acc, node, A1, tidx, DD, DD, NNODE * DD, DD, 1,
             blockIdx.y * 64, blockIdx.x * 64, As, Bs);
  __syncthreads();
  gemm_accum(acc, graph, A2, nullptr, 0, DD, DD, DD, 1,
             blockIdx.y * 64, blockIdx.x * 64, As, Bs);
  gemm_epilogue(acc, C, DD, 1.f, 0.f, 0, blockIdx.y * 64, blockIdx.x * 64);
}

// S[b,n,h] = node[b,n,:] . q16[b,h,:] via MFMA direct-from-global.
// CVT=1: node read f32, bf16 copy written to nb16_out.  CVT=0: node read bf16.
template <int CVT>
__global__ __launch_bounds__(128) void scores_kernel(
    const float* __restrict__ nodef, const unsigned short* __restrict__ nb16_in,
    unsigned short* __restrict__ nb16_out, const unsigned short* __restrict__ q16,
    float* __restrict__ S, int nh)
{
  const int b = blockIdx.y;
  const int t = threadIdx.x;
  const int w = t >> 6, lane = t & 63;
  const int tile = blockIdx.x * 2 + w;
  const int n0 = tile * 16;
  const int r16 = lane & 15;
  const int kg = (lane >> 4) * 8;
  const int arow = min(n0 + r16, NNODE - 1);   // clamp: dup rows, masked at store
  const int hb = min(r16, nh - 1);             // clamp: dup heads, masked at store
  const unsigned short* bp = q16 + ((long)b * nh + hb) * DD + kg;
  f32x4 acc = {0.f, 0.f, 0.f, 0.f};
  if (CVT) {
    const float* ap = nodef + ((long)b * NNODE + arow) * DD + kg;
    unsigned short* wp = nb16_out + ((long)b * NNODE + arow) * DD + kg;
#pragma unroll 4
    for (int s = 0; s < 16; ++s) {
      const float4 a0 = *(const float4*)(ap + s * 32);
      const float4 a1 = *(const float4*)(ap + s * 32 + 4);
      s16x8 af;
      af[0] = (short)f2bf(a0.x); af[1] = (short)f2bf(a0.y);
      af[2] = (short)f2bf(a0.z); af[3] = (short)f2bf(a0.w);
      af[4] = (short)f2bf(a1.x); af[5] = (short)f2bf(a1.y);
      af[6] = (short)f2bf(a1.z); af[7] = (short)f2bf(a1.w);
      *(s16x8*)(wp + s * 32) = af;             // bf16 node cache (dup-safe)
      const s16x8 bf = *(const s16x8*)(bp + s * 32);
      acc = __builtin_amdgcn_mfma_f32_16x16x32_bf16(af, bf, acc, 0, 0, 0);
    }
  } else {
    const unsigned short* ap = nb16_in + ((long)b * NNODE + arow) * DD + kg;
#pragma unroll 4
    for (int s = 0; s < 16; ++s) {
      const s16x8 af = *(const s16x8*)(ap + s * 32);
      const s16x8 bf = *(const s16x8*)(bp + s * 32);
      acc = __builtin_amdgcn_mfma_f32_16x16x32_bf16(af, bf, acc, 0, 0, 0);
    }
  }
  if (r16 < nh) {
#pragma unroll
    for (int r = 0; r < 4; ++r) {
      const int n = n0 + (lane >> 4) * 4 + r;
      if (n < NPAD) S[((long)b * NPAD + n) * nh + r16] = acc[r];
    }
  }
}

// Per-batch softmax over n per head; writes transposed probs Pt[b][n][h].
__global__ __launch_bounds__(64) void softmax_kernel(
    const float* __restrict__ S, float* __restrict__ Pt)
{
  const int b = blockIdx.x;
  const int lane = threadIdx.x;
  const int h = lane >> 3, sub = lane & 7;
  float v[13];
  float m = -3.0e38f;
#pragma unroll
  for (int k = 0; k < 13; ++k) {
    const int n = sub + 8 * k;
    v[k] = (n < NNODE) ? S[((long)b * NPAD + n) * NH + h] : -3.0e38f;
    m = fmaxf(m, v[k]);
  }
  m = fmaxf(m, __shfl_xor(m, 1));
  m = fmaxf(m, __shfl_xor(m, 2));
  m = fmaxf(m, __shfl_xor(m, 4));
  float e[13], sum = 0.f;
#pragma unroll
  for (int k = 0; k < 13; ++k) {
    const int n = sub + 8 * k;
    e[k] = (n < NNODE) ? __expf(v[k] - m) : 0.f;
    sum += e[k];
  }
  sum += __shfl_xor(sum, 1);
  sum += __shfl_xor(sum, 2);
  sum += __shfl_xor(sum, 4);
  const float inv = 1.f / sum;
#pragma unroll
  for (int k = 0; k < 13; ++k) {
    const int n = sub + 8 * k;
    if (n < NNODE) Pt[((long)b * NPAD + n) * NH + h] = e[k] * inv;
  }
  for (int i = lane; i < (NPAD - NNODE) * NH; i += 64)
    Pt[((long)b * NPAD + NNODE) * NH + i] = 0.f;
}

// ctx[b,h,d] = sum_n Pt[b,n,h] * node_bf16[b,n,d].  Streaming, bf16 node.
__global__ __launch_bounds__(128) void ctx_kernel(
    const unsigned short* __restrict__ nb16, const float* __restrict__ Pt,
    float* __restrict__ ctx)
{
  const int b = blockIdx.x;
  const int t = threadIdx.x;
  const int d0 = t * 4;
  __shared__ float shP[NPAD * NH];
  for (int i = t; i < NPAD * NH; i += 128) shP[i] = Pt[(long)b * NPAD * NH + i];
  __syncthreads();
  f32x4 cx[NH] = {};
  const unsigned short* nb = nb16 + (long)b * NNODE * DD + d0;
#pragma unroll 4
  for (int n = 0; n < NNODE; ++n) {
    const ushort4 nv = *(const ushort4*)(nb + (long)n * DD);
    f32x4 nf;
    nf[0] = bf2f(nv.x); nf[1] = bf2f(nv.y); nf[2] = bf2f(nv.z); nf[3] = bf2f(nv.w);
    const f32x4 p0 = *(const f32x4*)(&shP[n * NH]);
    const f32x4 p1 = *(const f32x4*)(&shP[n * NH + 4]);
    cx[0] += p0[0] * nf; cx[1] += p0[1] * nf;
    cx[2] += p0[2] * nf; cx[3] += p0[3] * nf;
    cx[4] += p1[0] * nf; cx[5] += p1[1] * nf;
    cx[6] += p1[2] * nf; cx[7] += p1[3] * nf;
  }
  float* cb = ctx + (long)b * NH * DD + d0;
#pragma unroll
  for (int h = 0; h < NH; ++h) *(f32x4*)(cb + h * DD) = cx[h];
}

// Final: lg[n] = 10*tanh(S2[n]) - mask*1e9; out = log_softmax(lg).
__global__ __launch_bounds__(64) void logits_fin(
    const float* __restrict__ S2, const int* __restrict__ mask,
    float* __restrict__ out)
{
  const int b = blockIdx.x;
  const int lane = threadIdx.x;
  float v0 = -3.0e38f, v1 = -3.0e38f;
  if (lane < NNODE)
    v0 = 10.f * tanhf(S2[(long)b * NPAD + lane]) - (float)mask[b * NNODE + lane] * 1e9f;
  if (lane + 64 < NNODE)
    v1 = 10.f * tanhf(S2[(long)b * NPAD + lane + 64]) - (float)mask[b * NNODE + lane + 64] * 1e9f;
  float mx = fmaxf(v0, v1);
#pragma unroll
  for (int off = 1; off < 64; off <<= 1) mx = fmaxf(mx, __shfl_xor(mx, off));
  float e = 0.f;
  if (lane < NNODE) e += __expf(v0 - mx);
  if (lane + 64 < NNODE) e += __expf(v1 - mx);
#pragma unroll
  for (int off = 1; off < 64; off <<= 1) e += __shfl_xor(e, off);
  const float lse = mx + __logf(e);
  float* ob = out + (long)b * NNODE;
  if (lane < NNODE) ob[lane] = v0 - lse;
  if (lane + 64 < NNODE) ob[lane + 64] = v1 - lse;
}

extern "C" void kernel_launch(void* const* d_in, const int* in_sizes, int n_in,
                              void* d_out, int out_size, void* d_ws, size_t ws_size,
                              hipStream_t stream) {
  const float* node     = (const float*)d_in[0];
  const float* graph    = (const float*)d_in[1];
  const int*   tidx     = (const int*)d_in[2];
  const int*   mask     = (const int*)d_in[3];
  const float* W_target = (const float*)d_in[4];
  const float* W_global = (const float*)d_in[5];
  const float* W_K1     = (const float*)d_in[6];
  const float* W_K2     = (const float*)d_in[7];
  const float* W_Q      = (const float*)d_in[8];
  const float* W_V      = (const float*)d_in[9];
  const float* Wq_mha   = (const float*)d_in[10];
  const float* Wk_mha   = (const float*)d_in[11];
  const float* Wv_mha   = (const float*)d_in[12];
  const float* Wo_mha   = (const float*)d_in[13];
  float* out = (float*)d_out;

  // workspace layout (float-element offsets); total ~296 MB (ws is ~1.6 GB)
  float* base = (float*)d_ws;
  unsigned short* nb16 = (unsigned short*)base;          // 2048*100*512 bf16
  long off = 2048L * NNODE * DD / 2;                     // in floats
  float* A1 = base + off;        off += 262144;
  float* A2 = base + off;        off += 262144;
  float* Wkc = base + off;       off += 262144;
  float* Wvc = base + off;       off += 262144;
  float* Woq = base + off;       off += 262144;
  float* qbuf = base + off;      off += 2048L * 512;
  unsigned short* qk16 = (unsigned short*)(base + off);  off += 2048L * 4096 / 2;
  float* Sbuf = base + off;      off += 2048L * NPAD * NH;
  float* Ptb = base + off;       off += 2048L * NPAD * NH;
  float* ctxb = base + off;      off += 2048L * 4096;
  float* preo = base + off;      off += 2048L * 512;
  float* query = base + off;     off += 2048L * 512;
  unsigned short* qk216 = (unsigned short*)(base + off); off += 2048L * 512 / 2;
  float* S2 = base + off;        off += 2048L * NPAD;

  dim3 blk(256);
  const float SH = 0.125f;               // 1/sqrt(64)
  const float SD = 0.044194173824f;      // 1/sqrt(512)

  // 5 weight folds in one launch
  Fold5Args fa;
  fa.A[0] = Wq_mha;  fa.B[0] = W_target; fa.C[0] = A1;  fa.al[0] = 1.f;
  fa.A[1] = Wq_mha;  fa.B[1] = W_global; fa.C[1] = A2;  fa.al[1] = 1.f;
  fa.A[2] = Wk_mha;  fa.B[2] = W_K1;     fa.C[2] = Wkc; fa.al[2] = SH;
  fa.A[3] = Wv_mha;  fa.B[3] = W_V;      fa.C[3] = Wvc; fa.al[3] = 1.f;
  fa.A[4] = W_Q;     fa.B[4] = Wo_mha;   fa.C[4] = Woq; fa.al[4] = 1.f;
  fold5_kernel<<<dim3(8, 8, 5), blk, 0, stream>>>(fa);
  // qbuf = tgt @ A1^T + graph @ A2^T (single launch)
  qbuf_kernel<<<dim3(8, 32), blk, 0, stream>>>(node, graph, tidx, A1, A2, qbuf);
  // qk16[b,h,:] = bf16( q[b, head h] @ Wkc[head h rows] )
  gemm_mfma<<<dim3(8, 32, 8), blk, 0, stream>>>(qbuf, Wkc, qk16,
      64, 512, 512, 4096, 64, 32768, 512, 0, 1.f, 0.f, 1);
  // scores + node->bf16 conversion (reads node f32 once)
  scores_kernel<1><<<dim3(4, 2048), dim3(128), 0, stream>>>(
      node, nullptr, nb16, qk16, Sbuf, NH);
  softmax_kernel<<<dim3(2048), dim3(64), 0, stream>>>(Sbuf, Ptb);
  ctx_kernel<<<dim3(2048), dim3(128), 0, stream>>>(nb16, Ptb, ctxb);
  // pre_o[b, head h] = ctx[b,h,:] @ Wvc[head h rows]^T
  gemm_mfma<<<dim3(1, 32, 8), blk, 0, stream>>>(ctxb, Wvc, preo,
      512, 4096, 512, 512, 512, 32768, 64, 1, 1.f, 0.f, 0);
  // query = pre_o @ Woq^T
  gemm_mfma<<<dim3(8, 32, 1), blk, 0, stream>>>(preo, Woq, query,
      512, 512, 512, 512, 0, 0, 0, 1, 1.f, 0.f, 0);
  // qk2 = bf16( (1/sqrt(D)) * query @ W_K2 )
  gemm_mfma<<<dim3(8, 32, 1), blk, 0, stream>>>(query, W_K2, qk216,
      512, 512, 512, 512, 0, 0, 0, 0, SD, 0.f, 1);
  // logit dots from bf16 node + finish
  scores_kernel<0><<<dim3(4, 2048), dim3(128), 0, stream>>>(
      nullptr, nb16, nullptr, qk216, S2, 1);
  logits_fin<<<dim3(2048), dim3(64), 0, stream>>>(S2, mask, out);

  (void)in_sizes; (void)n_in; (void)out_size; (void)ws_size;
}

// Round 4
// 340.173 us; speedup vs baseline: 2.2019x; 1.2146x over previous
//
#include <hip/hip_runtime.h>

#define DD 512
#define NNODE 100
#define NH 8

typedef __attribute__((ext_vector_type(4))) float f32x4;
typedef __attribute__((ext_vector_type(8))) short s16x8;

__device__ __forceinline__ unsigned short f2bf(float x) {
  union { float f; unsigned int u; } v; v.f = x;
  unsigned int r = v.u + 0x7fffu + ((v.u >> 16) & 1u);
  return (unsigned short)(r >> 16);
}
__device__ __forceinline__ float bf2f(unsigned short u) {
  union { unsigned int u; float f; } v; v.u = ((unsigned int)u) << 16;
  return v.f;
}

// ---- shared GEMM core: 64x64 tile, 4 waves, bf16 MFMA 16x16x32 ----
__device__ __forceinline__ void gemm_accum(
    f32x4 acc[2][2], const float* __restrict__ A, const float* __restrict__ B,
    const int* __restrict__ gidx, int gmul, int K, int lda, int ldb,
    int transB, int m0, int n0,
    unsigned short (*As)[40], unsigned short (*Bs)[40])
{
  const int t = threadIdx.x;
  const int wid = t >> 6, lane = t & 63;
  const int wr = wid >> 1, wc = wid & 1;
  const int r16 = lane & 15, kg = (lane >> 4) * 8;
  const int tr = t >> 3, kq = t & 7;
  const int bn = t & 63, bk = t >> 6;

  for (int k0 = 0; k0 < K; k0 += 32) {
#pragma unroll
    for (int rp = 0; rp < 2; ++rp) {
      const int row = tr + rp * 32;
      const int gi = m0 + row;
      long ab = (long)gi * lda;
      if (gidx) ab += (long)gidx[gi] * gmul;
      const float4 av = *(const float4*)(A + ab + k0 + kq * 4);
      unsigned int p0 = (unsigned)f2bf(av.x) | ((unsigned)f2bf(av.y) << 16);
      unsigned int p1 = (unsigned)f2bf(av.z) | ((unsigned)f2bf(av.w) << 16);
      *(uint2*)(&As[row][kq * 4]) = make_uint2(p0, p1);
    }
    if (transB) {
#pragma unroll
      for (int rp = 0; rp < 2; ++rp) {
        const int row = tr + rp * 32;
        const float4 bv = *(const float4*)(B + (long)(n0 + row) * ldb + k0 + kq * 4);
        unsigned int p0 = (unsigned)f2bf(bv.x) | ((unsigned)f2bf(bv.y) << 16);
        unsigned int p1 = (unsigned)f2bf(bv.z) | ((unsigned)f2bf(bv.w) << 16);
        *(uint2*)(&Bs[row][kq * 4]) = make_uint2(p0, p1);
      }
    } else {
#pragma unroll
      for (int pp = 0; pp < 8; ++pp) {
        const int k = bk + pp * 4;
        Bs[bn][k] = f2bf(B[(long)(k0 + k) * ldb + n0 + bn]);
      }
    }
    __syncthreads();
    s16x8 a0 = *(const s16x8*)(&As[wr * 32 + r16][kg]);
    s16x8 a1 = *(const s16x8*)(&As[wr * 32 + 16 + r16][kg]);
    s16x8 b0 = *(const s16x8*)(&Bs[wc * 32 + r16][kg]);
    s16x8 b1 = *(const s16x8*)(&Bs[wc * 32 + 16 + r16][kg]);
    acc[0][0] = __builtin_amdgcn_mfma_f32_16x16x32_bf16(a0, b0, acc[0][0], 0, 0, 0);
    acc[0][1] = __builtin_amdgcn_mfma_f32_16x16x32_bf16(a0, b1, acc[0][1], 0, 0, 0);
    acc[1][0] = __builtin_amdgcn_mfma_f32_16x16x32_bf16(a1, b0, acc[1][0], 0, 0, 0);
    acc[1][1] = __builtin_amdgcn_mfma_f32_16x16x32_bf16(a1, b1, acc[1][1], 0, 0, 0);
    __syncthreads();
  }
}

__device__ __forceinline__ void gemm_epilogue(
    f32x4 acc[2][2], void* Cv, int ldc, float alpha, float beta, int obf16,
    int m0, int n0)
{
  const int t = threadIdx.x;
  const int wid = t >> 6, lane = t & 63;
  const int wr = wid >> 1, wc = wid & 1;
  const int r16 = lane & 15;
#pragma unroll
  for (int si = 0; si < 2; ++si)
#pragma unroll
    for (int sj = 0; sj < 2; ++sj)
#pragma unroll
      for (int r = 0; r < 4; ++r) {
        const int row = m0 + wr * 32 + si * 16 + (lane >> 4) * 4 + r;
        const int col = n0 + wc * 32 + sj * 16 + r16;
        const long ci = (long)row * ldc + col;
        float v = alpha * acc[si][sj][r];
        if (obf16) {
          ((unsigned short*)Cv)[ci] = f2bf(v);
        } else {
          float* C = (float*)Cv;
          if (beta != 0.f) v = fmaf(beta, C[ci], v);
          C[ci] = v;
        }
      }
}

__global__ __launch_bounds__(256) void gemm_mfma(
    const float* __restrict__ A, const float* __restrict__ B, void* Cv,
    int K, int lda, int ldb, int ldc,
    long aoffz, long boffz, long coffz,
    int transB, float alpha, float beta, int obf16)
{
  __shared__ unsigned short As[64][40];
  __shared__ unsigned short Bs[64][40];
  A += (long)blockIdx.z * aoffz;
  B += (long)blockIdx.z * boffz;
  f32x4 acc[2][2] = {};
  gemm_accum(acc, A, B, nullptr, 0, K, lda, ldb, transB,
             blockIdx.y * 64, blockIdx.x * 64, As, Bs);
  void* Cz = obf16 ? (void*)((unsigned short*)Cv + (long)blockIdx.z * coffz)
                   : (void*)((float*)Cv + (long)blockIdx.z * coffz);
  gemm_epilogue(acc, Cz, ldc, alpha, beta, obf16, blockIdx.y * 64, blockIdx.x * 64);
}

struct Fold5Args {
  const float* A[5]; const float* B[5]; float* C[5]; float al[5];
};

__global__ __launch_bounds__(256) void fold5_kernel(Fold5Args fa) {
  __shared__ unsigned short As[64][40];
  __shared__ unsigned short Bs[64][40];
  const int z = blockIdx.z;
  f32x4 acc[2][2] = {};
  gemm_accum(acc, fa.A[z], fa.B[z], nullptr, 0, 512, 512, 512, 0,
             blockIdx.y * 64, blockIdx.x * 64, As, Bs);
  gemm_epilogue(acc, fa.C[z], 512, fa.al[z], 0.f, 0, blockIdx.y * 64, blockIdx.x * 64);
}

__global__ __launch_bounds__(256) void qbuf_kernel(
    const float* __restrict__ node, const float* __restrict__ graph,
    const int* __restrict__ tidx, const float* __restrict__ A1,
    const float* __restrict__ A2, float* __restrict__ C)
{
  __shared__ unsigned short As[64][40];
  __shared__ unsigned short Bs[64][40];
  f32x4 acc[2][2] = {};
  gemm_accum(acc, node, A1, tidx, DD, DD, NNODE * DD, DD, 1,
             blockIdx.y * 64, blockIdx.x * 64, As, Bs);
  __syncthreads();
  gemm_accum(acc, graph, A2, nullptr, 0, DD, DD, DD, 1,
             blockIdx.y * 64, blockIdx.x * 64, As, Bs);
  gemm_epilogue(acc, C, DD, 1.f, 0.f, 0, blockIdx.y * 64, blockIdx.x * 64);
}

// ---- fused attention: node f32 -> bf16 (LDS frag layout + nb16 global),
// scores via MFMA, online softmax (per-wave redundant), ctx accumulate.
// One block per batch, 256 threads = 4 waves.
__global__ __launch_bounds__(256) void attn_fused(
    const float* __restrict__ node, const unsigned short* __restrict__ qk16,
    unsigned short* __restrict__ nb16, float* __restrict__ ctx)
{
  const int b = blockIdx.x;
  const int t = threadIdx.x;
  const int lane = t & 63;
  const int wid = t >> 6;
  const int r16 = lane & 15;
  const int rg = lane >> 4;

  __shared__ unsigned short nf[16 * 512];   // node chunk, frag layout, 16 KB
  __shared__ unsigned short qf[16 * 512];   // qk frags, 16 KB
  __shared__ float Pl[4][16][8];
  __shared__ float rfl[4][8];

  // stage qk fragments once (heads 8..15 zero)
  {
    const unsigned short* qb = qk16 + (long)b * (NH * DD);
    for (int slot = t; slot < 1024; slot += 256) {
      const int s = slot >> 6, vl = slot & 63;
      const int h = vl & 15, g = vl >> 4;
      s16x8 v = {0, 0, 0, 0, 0, 0, 0, 0};
      if (h < NH) v = *(const s16x8*)(qb + h * DD + s * 32 + g * 8);
      *(s16x8*)(&qf[slot * 8]) = v;
    }
  }

  // staging-thread geometry: thread holds rows {r0+2i}, cols c4..c4+3
  const int r0 = t >> 7;
  const int c4 = (t * 4) & 511;
  const int s_c = c4 >> 5, rg_c = (c4 >> 3) & 3, j_c = c4 & 7;
  const int slotbase = (s_c * 4 + rg_c) * 16 + r0;
  // ctx-phase geometry: thread owns d0 = 2t
  const int d0 = t * 2;
  const int cbase = ((d0 >> 5) * 4 + ((d0 >> 3) & 3)) * 128 + (d0 & 7);
  // mfma frag base for (rg, r16)
  const int fb = (rg * 16 + r16) * 8;

  const float* nbase = node + (long)b * (NNODE * DD);
  float4 rs[8];
  {
    const int lim = NNODE * DD;
#pragma unroll
    for (int i = 0; i < 8; ++i) {
      const int e = 4 * t + 1024 * i;
      rs[i] = (e < lim) ? *(const float4*)(nbase + e) : make_float4(0.f, 0.f, 0.f, 0.f);
    }
  }

  float m = -3.0e38f, l = 0.f;
  float2 c2[NH];
#pragma unroll
  for (int h = 0; h < NH; ++h) { c2[h].x = 0.f; c2[h].y = 0.f; }

  for (int c = 0; c < 7; ++c) {
    const int c0 = c * 16;
    __syncthreads();                        // nf free (prev chunk consumed)
    // convert staged regs -> LDS frag layout + global nb16
#pragma unroll
    for (int i = 0; i < 8; ++i) {
      ushort4 h4;
      h4.x = f2bf(rs[i].x); h4.y = f2bf(rs[i].y);
      h4.z = f2bf(rs[i].z); h4.w = f2bf(rs[i].w);
      *(ushort4*)(&nf[(slotbase + 2 * i) * 8 + j_c]) = h4;
      const int row = r0 + 2 * i;
      if (c0 + row < NNODE)
        *(ushort4*)(nb16 + ((long)b * NNODE + c0 + row) * DD + c4) = h4;
    }
    // prefetch next chunk (loads in flight during compute)
    if (c < 6) {
      const int nc0 = c0 + 16;
      const int lim = (NNODE - nc0) * DD;
#pragma unroll
      for (int i = 0; i < 8; ++i) {
        const int e = 4 * t + 1024 * i;
        rs[i] = (e < lim) ? *(const float4*)(nbase + (long)nc0 * DD + e)
                          : make_float4(0.f, 0.f, 0.f, 0.f);
      }
    }
    __syncthreads();                        // nf ready

    // scores for this chunk (every wave, redundant)
    f32x4 acc = {0.f, 0.f, 0.f, 0.f};
#pragma unroll
    for (int s = 0; s < 16; ++s) {
      const s16x8 av = *(const s16x8*)(&nf[s * 512 + fb]);
      const s16x8 bv = *(const s16x8*)(&qf[s * 512 + fb]);
      acc = __builtin_amdgcn_mfma_f32_16x16x32_bf16(av, bv, acc, 0, 0, 0);
    }
#pragma unroll
    for (int r = 0; r < 4; ++r)
      if (c0 + rg * 4 + r >= NNODE) acc[r] = -3.0e38f;

    // online softmax (per head column r16; 4 redundant lane-groups)
    float cm = fmaxf(fmaxf(acc[0], acc[1]), fmaxf(acc[2], acc[3]));
    cm = fmaxf(cm, __shfl_xor(cm, 16));
    cm = fmaxf(cm, __shfl_xor(cm, 32));
    const float mn = fmaxf(m, cm);
    const float rf = __expf(m - mn);
    float p[4], ps = 0.f;
#pragma unroll
    for (int r = 0; r < 4; ++r) { p[r] = __expf(acc[r] - mn); ps += p[r]; }
    ps += __shfl_xor(ps, 16);
    ps += __shfl_xor(ps, 32);
    l = l * rf + ps;
    m = mn;
    if (r16 < NH) {
#pragma unroll
      for (int r = 0; r < 4; ++r) Pl[wid][rg * 4 + r][r16] = p[r];
      if (rg == 0) rfl[wid][r16] = rf;
    }
    asm volatile("s_waitcnt lgkmcnt(0)" ::: "memory");

    // ctx update (all lanes): rescale + accumulate chunk
    {
      const f32x4 rf0 = *(const f32x4*)(&rfl[wid][0]);
      const f32x4 rf1 = *(const f32x4*)(&rfl[wid][4]);
#pragma unroll
      for (int h = 0; h < 4; ++h) { c2[h].x *= rf0[h]; c2[h].y *= rf0[h]; }
#pragma unroll
      for (int h = 0; h < 4; ++h) { c2[4 + h].x *= rf1[h]; c2[4 + h].y *= rf1[h]; }
#pragma unroll
      for (int n = 0; n < 16; ++n) {
        const unsigned int nv = *(const unsigned int*)(&nf[cbase + n * 8]);
        const float x0 = bf2f((unsigned short)(nv & 0xffffu));
        const float x1 = bf2f((unsigned short)(nv >> 16));
        const f32x4 p0 = *(const f32x4*)(&Pl[wid][n][0]);
        const f32x4 p1 = *(const f32x4*)(&Pl[wid][n][4]);
#pragma unroll
        for (int h = 0; h < 4; ++h) {
          c2[h].x = fmaf(p0[h], x0, c2[h].x);
          c2[h].y = fmaf(p0[h], x1, c2[h].y);
          c2[4 + h].x = fmaf(p1[h], x0, c2[4 + h].x);
          c2[4 + h].y = fmaf(p1[h], x1, c2[4 + h].y);
        }
      }
    }
  }

  // finalize: scale by 1/l and write ctx
  if (r16 < NH && rg == 0) rfl[wid][r16] = 1.f / l;
  asm volatile("s_waitcnt lgkmcnt(0)" ::: "memory");
  {
    const f32x4 i0 = *(const f32x4*)(&rfl[wid][0]);
    const f32x4 i1 = *(const f32x4*)(&rfl[wid][4]);
    float* cb = ctx + (long)b * (NH * DD) + d0;
#pragma unroll
    for (int h = 0; h < 4; ++h) {
      cb[h * DD] = c2[h].x * i0[h];
      cb[h * DD + 1] = c2[h].y * i0[h];
      cb[(4 + h) * DD] = c2[4 + h].x * i1[h];
      cb[(4 + h) * DD + 1] = c2[4 + h].y * i1[h];
    }
  }
}

// ---- fused logits: dots from bf16 node via MFMA + tanh/mask/log_softmax ----
__global__ __launch_bounds__(128) void logits_kernel(
    const unsigned short* __restrict__ nb16, const unsigned short* __restrict__ qk216,
    const int* __restrict__ mask, float* __restrict__ out)
{
  const int b = blockIdx.x;
  const int t = threadIdx.x;
  const int wid = t >> 6, lane = t & 63;
  const int r16 = lane & 15, rg = lane >> 4;
  __shared__ float sl[112];
  const unsigned short* qb = qk216 + (long)b * DD + rg * 8;

  for (int ti = wid; ti < 7; ti += 2) {
    const int arow = min(ti * 16 + r16, NNODE - 1);
    const unsigned short* ap = nb16 + ((long)b * NNODE + arow) * DD + rg * 8;
    f32x4 acc = {0.f, 0.f, 0.f, 0.f};
#pragma unroll
    for (int s = 0; s < 16; ++s) {
      const s16x8 av = *(const s16x8*)(ap + s * 32);
      const s16x8 bv = *(const s16x8*)(qb + s * 32);
      acc = __builtin_amdgcn_mfma_f32_16x16x32_bf16(av, bv, acc, 0, 0, 0);
    }
    if (r16 == 0) {
#pragma unroll
      for (int r = 0; r < 4; ++r) {
        const int n = ti * 16 + rg * 4 + r;
        if (n < 112) sl[n] = acc[r];
      }
    }
  }
  __syncthreads();
  if (t < 64) {
    float v0 = -3.0e38f, v1 = -3.0e38f;
    if (lane < NNODE)
      v0 = 10.f * tanhf(sl[lane]) - (float)mask[b * NNODE + lane] * 1e9f;
    if (lane + 64 < NNODE)
      v1 = 10.f * tanhf(sl[lane + 64]) - (float)mask[b * NNODE + lane + 64] * 1e9f;
    float mx = fmaxf(v0, v1);
#pragma unroll
    for (int off = 1; off < 64; off <<= 1) mx = fmaxf(mx, __shfl_xor(mx, off));
    float e = 0.f;
    if (lane < NNODE) e += __expf(v0 - mx);
    if (lane + 64 < NNODE) e += __expf(v1 - mx);
#pragma unroll
    for (int off = 1; off < 64; off <<= 1) e += __shfl_xor(e, off);
    const float lse = mx + __logf(e);
    float* ob = out + (long)b * NNODE;
    if (lane < NNODE) ob[lane] = v0 - lse;
    if (lane + 64 < NNODE) ob[lane + 64] = v1 - lse;
  }
}

extern "C" void kernel_launch(void* const* d_in, const int* in_sizes, int n_in,
                              void* d_out, int out_size, void* d_ws, size_t ws_size,
                              hipStream_t stream) {
  const float* node     = (const float*)d_in[0];
  const float* graph    = (const float*)d_in[1];
  const int*   tidx     = (const int*)d_in[2];
  const int*   mask     = (const int*)d_in[3];
  const float* W_target = (const float*)d_in[4];
  const float* W_global = (const float*)d_in[5];
  const float* W_K1     = (const float*)d_in[6];
  const float* W_K2     = (const float*)d_in[7];
  const float* W_Q      = (const float*)d_in[8];
  const float* W_V      = (const float*)d_in[9];
  const float* Wq_mha   = (const float*)d_in[10];
  const float* Wk_mha   = (const float*)d_in[11];
  const float* Wv_mha   = (const float*)d_in[12];
  const float* Wo_mha   = (const float*)d_in[13];
  float* out = (float*)d_out;

  float* base = (float*)d_ws;
  unsigned short* nb16 = (unsigned short*)base;          // 2048*100*512 bf16
  long off = 2048L * NNODE * DD / 2;                     // in floats
  float* A1 = base + off;        off += 262144;
  float* A2 = base + off;        off += 262144;
  float* Wkc = base + off;       off += 262144;
  float* Wvc = base + off;       off += 262144;
  float* Woq = base + off;       off += 262144;
  float* qbuf = base + off;      off += 2048L * 512;
  unsigned short* qk16 = (unsigned short*)(base + off);  off += 2048L * 4096 / 2;
  float* ctxb = base + off;      off += 2048L * 4096;
  float* preo = base + off;      off += 2048L * 512;
  float* query = base + off;     off += 2048L * 512;
  unsigned short* qk216 = (unsigned short*)(base + off); off += 2048L * 512 / 2;

  dim3 blk(256);
  const float SH = 0.125f;               // 1/sqrt(64)
  const float SD = 0.044194173824f;      // 1/sqrt(512)

  Fold5Args fa;
  fa.A[0] = Wq_mha;  fa.B[0] = W_target; fa.C[0] = A1;  fa.al[0] = 1.f;
  fa.A[1] = Wq_mha;  fa.B[1] = W_global; fa.C[1] = A2;  fa.al[1] = 1.f;
  fa.A[2] = Wk_mha;  fa.B[2] = W_K1;     fa.C[2] = Wkc; fa.al[2] = SH;
  fa.A[3] = Wv_mha;  fa.B[3] = W_V;      fa.C[3] = Wvc; fa.al[3] = 1.f;
  fa.A[4] = W_Q;     fa.B[4] = Wo_mha;   fa.C[4] = Woq; fa.al[4] = 1.f;
  fold5_kernel<<<dim3(8, 8, 5), blk, 0, stream>>>(fa);
  qbuf_kernel<<<dim3(8, 32), blk, 0, stream>>>(node, graph, tidx, A1, A2, qbuf);
  gemm_mfma<<<dim3(8, 32, 8), blk, 0, stream>>>(qbuf, Wkc, qk16,
      64, 512, 512, 4096, 64, 32768, 512, 0, 1.f, 0.f, 1);
  // fused attention (node streamed once, bf16 cache written for logit pass)
  attn_fused<<<dim3(2048), dim3(256), 0, stream>>>(node, qk16, nb16, ctxb);
  gemm_mfma<<<dim3(1, 32, 8), blk, 0, stream>>>(ctxb, Wvc, preo,
      512, 4096, 512, 512, 512, 32768, 64, 1, 1.f, 0.f, 0);
  gemm_mfma<<<dim3(8, 32, 1), blk, 0, stream>>>(preo, Woq, query,
      512, 512, 512, 512, 0, 0, 0, 1, 1.f, 0.f, 0);
  gemm_mfma<<<dim3(8, 32, 1), blk, 0, stream>>>(query, W_K2, qk216,
      512, 512, 512, 512, 0, 0, 0, 0, SD, 0.f, 1);
  // fused logit pass
  logits_kernel<<<dim3(2048), dim3(128), 0, stream>>>(nb16, qk216, mask, out);

  (void)in_sizes; (void)n_in; (void)out_size; (void)ws_size;
}

// Round 5
// 338.813 us; speedup vs baseline: 2.2107x; 1.0040x over previous
//
#include <hip/hip_runtime.h>

#define DD 512
#define NNODE 100
#define NH 8

typedef __attribute__((ext_vector_type(4))) float f32x4;
typedef __attribute__((ext_vector_type(8))) short s16x8;

__device__ __forceinline__ unsigned short f2bf(float x) {
  union { float f; unsigned int u; } v; v.f = x;
  unsigned int r = v.u + 0x7fffu + ((v.u >> 16) & 1u);
  return (unsigned short)(r >> 16);
}
__device__ __forceinline__ float bf2f(unsigned short u) {
  union { unsigned int u; float f; } v; v.u = ((unsigned int)u) << 16;
  return v.f;
}

// ---- shared GEMM core: 64x64 tile, 4 waves, bf16 MFMA 16x16x32 ----
__device__ __forceinline__ void gemm_accum(
    f32x4 acc[2][2], const float* __restrict__ A, const float* __restrict__ B,
    const int* __restrict__ gidx, int gmul, int K, int lda, int ldb,
    int transB, int m0, int n0,
    unsigned short (*As)[40], unsigned short (*Bs)[40])
{
  const int t = threadIdx.x;
  const int wid = t >> 6, lane = t & 63;
  const int wr = wid >> 1, wc = wid & 1;
  const int r16 = lane & 15, kg = (lane >> 4) * 8;
  const int tr = t >> 3, kq = t & 7;
  const int bn = t & 63, bk = t >> 6;

  for (int k0 = 0; k0 < K; k0 += 32) {
#pragma unroll
    for (int rp = 0; rp < 2; ++rp) {
      const int row = tr + rp * 32;
      const int gi = m0 + row;
      long ab = (long)gi * lda;
      if (gidx) ab += (long)gidx[gi] * gmul;
      const float4 av = *(const float4*)(A + ab + k0 + kq * 4);
      unsigned int p0 = (unsigned)f2bf(av.x) | ((unsigned)f2bf(av.y) << 16);
      unsigned int p1 = (unsigned)f2bf(av.z) | ((unsigned)f2bf(av.w) << 16);
      *(uint2*)(&As[row][kq * 4]) = make_uint2(p0, p1);
    }
    if (transB) {
#pragma unroll
      for (int rp = 0; rp < 2; ++rp) {
        const int row = tr + rp * 32;
        const float4 bv = *(const float4*)(B + (long)(n0 + row) * ldb + k0 + kq * 4);
        unsigned int p0 = (unsigned)f2bf(bv.x) | ((unsigned)f2bf(bv.y) << 16);
        unsigned int p1 = (unsigned)f2bf(bv.z) | ((unsigned)f2bf(bv.w) << 16);
        *(uint2*)(&Bs[row][kq * 4]) = make_uint2(p0, p1);
      }
    } else {
#pragma unroll
      for (int pp = 0; pp < 8; ++pp) {
        const int k = bk + pp * 4;
        Bs[bn][k] = f2bf(B[(long)(k0 + k) * ldb + n0 + bn]);
      }
    }
    __syncthreads();
    s16x8 a0 = *(const s16x8*)(&As[wr * 32 + r16][kg]);
    s16x8 a1 = *(const s16x8*)(&As[wr * 32 + 16 + r16][kg]);
    s16x8 b0 = *(const s16x8*)(&Bs[wc * 32 + r16][kg]);
    s16x8 b1 = *(const s16x8*)(&Bs[wc * 32 + 16 + r16][kg]);
    acc[0][0] = __builtin_amdgcn_mfma_f32_16x16x32_bf16(a0, b0, acc[0][0], 0, 0, 0);
    acc[0][1] = __builtin_amdgcn_mfma_f32_16x16x32_bf16(a0, b1, acc[0][1], 0, 0, 0);
    acc[1][0] = __builtin_amdgcn_mfma_f32_16x16x32_bf16(a1, b0, acc[1][0], 0, 0, 0);
    acc[1][1] = __builtin_amdgcn_mfma_f32_16x16x32_bf16(a1, b1, acc[1][1], 0, 0, 0);
    __syncthreads();
  }
}

__device__ __forceinline__ void gemm_epilogue(
    f32x4 acc[2][2], void* Cv, int ldc, float alpha, float beta, int obf16,
    int m0, int n0)
{
  const int t = threadIdx.x;
  const int wid = t >> 6, lane = t & 63;
  const int wr = wid >> 1, wc = wid & 1;
  const int r16 = lane & 15;
#pragma unroll
  for (int si = 0; si < 2; ++si)
#pragma unroll
    for (int sj = 0; sj < 2; ++sj)
#pragma unroll
      for (int r = 0; r < 4; ++r) {
        const int row = m0 + wr * 32 + si * 16 + (lane >> 4) * 4 + r;
        const int col = n0 + wc * 32 + sj * 16 + r16;
        const long ci = (long)row * ldc + col;
        float v = alpha * acc[si][sj][r];
        if (obf16) {
          ((unsigned short*)Cv)[ci] = f2bf(v);
        } else {
          float* C = (float*)Cv;
          if (beta != 0.f) v = fmaf(beta, C[ci], v);
          C[ci] = v;
        }
      }
}

__global__ __launch_bounds__(256) void gemm_mfma(
    const float* __restrict__ A, const float* __restrict__ B, void* Cv,
    int K, int lda, int ldb, int ldc,
    long aoffz, long boffz, long coffz,
    int transB, float alpha, float beta, int obf16)
{
  __shared__ unsigned short As[64][40];
  __shared__ unsigned short Bs[64][40];
  A += (long)blockIdx.z * aoffz;
  B += (long)blockIdx.z * boffz;
  f32x4 acc[2][2] = {};
  gemm_accum(acc, A, B, nullptr, 0, K, lda, ldb, transB,
             blockIdx.y * 64, blockIdx.x * 64, As, Bs);
  void* Cz = obf16 ? (void*)((unsigned short*)Cv + (long)blockIdx.z * coffz)
                   : (void*)((float*)Cv + (long)blockIdx.z * coffz);
  gemm_epilogue(acc, Cz, ldc, alpha, beta, obf16, blockIdx.y * 64, blockIdx.x * 64);
}

struct Fold5Args {
  const float* A[5]; const float* B[5]; float* C[5]; float al[5];
};

__global__ __launch_bounds__(256) void fold5_kernel(Fold5Args fa) {
  __shared__ unsigned short As[64][40];
  __shared__ unsigned short Bs[64][40];
  const int z = blockIdx.z;
  f32x4 acc[2][2] = {};
  gemm_accum(acc, fa.A[z], fa.B[z], nullptr, 0, 512, 512, 512, 0,
             blockIdx.y * 64, blockIdx.x * 64, As, Bs);
  gemm_epilogue(acc, fa.C[z], 512, fa.al[z], 0.f, 0, blockIdx.y * 64, blockIdx.x * 64);
}

__global__ __launch_bounds__(256) void qbuf_kernel(
    const float* __restrict__ node, const float* __restrict__ graph,
    const int* __restrict__ tidx, const float* __restrict__ A1,
    const float* __restrict__ A2, float* __restrict__ C)
{
  __shared__ unsigned short As[64][40];
  __shared__ unsigned short Bs[64][40];
  f32x4 acc[2][2] = {};
  gemm_accum(acc, node, A1, tidx, DD, DD, NNODE * DD, DD, 1,
             blockIdx.y * 64, blockIdx.x * 64, As, Bs);
  __syncthreads();
  gemm_accum(acc, graph, A2, nullptr, 0, DD, DD, DD, 1,
             blockIdx.y * 64, blockIdx.x * 64, As, Bs);
  gemm_epilogue(acc, C, DD, 1.f, 0.f, 0, blockIdx.y * 64, blockIdx.x * 64);
}

// ---- fused attention. One block per batch, 256 thr = 4 waves.
// Double-buffered node-chunk LDS (1 barrier/chunk); loads never cross a
// barrier; XOR slot-swizzle kills the ctx-phase bank collapse.
__global__ __launch_bounds__(256) void attn_fused(
    const float* __restrict__ node, const unsigned short* __restrict__ qk16,
    unsigned short* __restrict__ nb16, float* __restrict__ ctx)
{
  const int b = blockIdx.x;
  const int t = threadIdx.x;
  const int lane = t & 63;
  const int wid = t >> 6;
  const int r16 = lane & 15;
  const int rg = lane >> 4;

  __shared__ unsigned short nf[2][16 * 512];      // 2 x 16 KB, slot-swizzled
  __shared__ unsigned short qf[16 * 288];         // [s][idx 0..31 +pad] 9 KB
  __shared__ float Pl[4][16][8];
  __shared__ float rfl[4][8];

  // stage qk fragments: qf[s*288 + idx*8 + (idx>>3)*8], idx = h*4+g
  {
    const unsigned short* qb = qk16 + (long)b * (NH * DD);
    for (int slot = t; slot < 512; slot += 256) {
      const int s = slot >> 5;
      const int idx = slot & 31;           // h*4+g
      const int h = idx >> 2, g = idx & 3;
      *(s16x8*)(&qf[s * 288 + idx * 8 + (idx >> 3) * 8]) =
          *(const s16x8*)(qb + h * DD + s * 32 + g * 8);
    }
  }

  // staging geometry: thread holds rows {r0+2i}, cols c4..c4+3
  const int r0 = t >> 7;
  const int c4 = (t * 4) & 511;
  const int slotbase = ((c4 >> 3) * 16) + r0;     // combo*16 + row
  const int j_c = c4 & 7;
  // ctx geometry: thread owns d0 = 2t (2 consecutive d)
  const int d0 = t * 2;
  const int cslot0 = (d0 >> 3) * 16;              // + n, then swizzle
  const int cxor = (d0 >> 3) & 7;
  const int cj = d0 & 7;
  // qf read base for (h=r16, g=rg)
  const int qidx = (r16 & 7) * 4 + rg;
  const int qfb = qidx * 8 + (qidx >> 3) * 8;

  const float* nbase = node + (long)b * (NNODE * DD);
  float4 rs[8];
  {
    const int lim = NNODE * DD;
#pragma unroll
    for (int i = 0; i < 8; ++i) {
      const int e = 4 * t + 1024 * i;
      rs[i] = (e < lim) ? *(const float4*)(nbase + e) : make_float4(0.f, 0.f, 0.f, 0.f);
    }
  }

  float m = -3.0e38f, l = 0.f;
  float2 c2[NH];
#pragma unroll
  for (int h = 0; h < NH; ++h) { c2[h].x = 0.f; c2[h].y = 0.f; }
  ushort4 h4s[8];

  for (int c = 0; c < 7; ++c) {
    const int c0 = c * 16;
    const int cur = c & 1;
    // cvt staged regs -> LDS (swizzled slots); keep bf16 in regs for stores
#pragma unroll
    for (int i = 0; i < 8; ++i) {
      ushort4 h4;
      h4.x = f2bf(rs[i].x); h4.y = f2bf(rs[i].y);
      h4.z = f2bf(rs[i].z); h4.w = f2bf(rs[i].w);
      h4s[i] = h4;
      const int slot = slotbase + 2 * i;
      const int phys = slot ^ ((slot >> 4) & 7);
      *(ushort4*)(&nf[cur][phys * 8 + j_c]) = h4;
    }
    __syncthreads();
    // issue next-chunk loads (consumed next iter; never cross a barrier)
    if (c < 6) {
      const int nc0 = c0 + 16;
      const int lim = (NNODE - nc0) * DD;
#pragma unroll
      for (int i = 0; i < 8; ++i) {
        const int e = 4 * t + 1024 * i;
        rs[i] = (e < lim) ? *(const float4*)(nbase + (long)nc0 * DD + e)
                          : make_float4(0.f, 0.f, 0.f, 0.f);
      }
    }
    // issue nb16 stores (drain at NEXT barrier, ~full chunk later)
#pragma unroll
    for (int i = 0; i < 8; ++i) {
      const int row = r0 + 2 * i;
      if (c0 + row < NNODE)
        *(ushort4*)(nb16 + ((long)b * NNODE + c0 + row) * DD + c4) = h4s[i];
    }

    // scores via MFMA (every wave redundant; heads>=8 predicated to zero)
    f32x4 acc = {0.f, 0.f, 0.f, 0.f};
#pragma unroll
    for (int s = 0; s < 16; ++s) {
      const int slr = (s * 4 + rg) * 16 + r16;
      const s16x8 av = *(const s16x8*)(&nf[cur][(slr ^ ((s * 4 + rg) & 7)) * 8]);
      s16x8 bv = {0, 0, 0, 0, 0, 0, 0, 0};
      if (r16 < NH) bv = *(const s16x8*)(&qf[s * 288 + qfb]);
      acc = __builtin_amdgcn_mfma_f32_16x16x32_bf16(av, bv, acc, 0, 0, 0);
    }
#pragma unroll
    for (int r = 0; r < 4; ++r)
      if (c0 + rg * 4 + r >= NNODE) acc[r] = -3.0e38f;

    // online softmax per head col r16 (reduce over rg via lane^16/^32)
    float cm = fmaxf(fmaxf(acc[0], acc[1]), fmaxf(acc[2], acc[3]));
    cm = fmaxf(cm, __shfl_xor(cm, 16));
    cm = fmaxf(cm, __shfl_xor(cm, 32));
    const float mn = fmaxf(m, cm);
    const float rf = __expf(m - mn);
    float p[4], ps = 0.f;
#pragma unroll
    for (int r = 0; r < 4; ++r) { p[r] = __expf(acc[r] - mn); ps += p[r]; }
    ps += __shfl_xor(ps, 16);
    ps += __shfl_xor(ps, 32);
    l = l * rf + ps;
    m = mn;
    if (r16 < NH) {
#pragma unroll
      for (int r = 0; r < 4; ++r) Pl[wid][rg * 4 + r][r16] = p[r];
      if (rg == 0) rfl[wid][r16] = rf;
    }
    asm volatile("s_waitcnt lgkmcnt(0)" ::: "memory");

    // ctx update: rescale + accumulate (swizzled nv reads, conflict-free)
    {
      const f32x4 rf0 = *(const f32x4*)(&rfl[wid][0]);
      const f32x4 rf1 = *(const f32x4*)(&rfl[wid][4]);
#pragma unroll
      for (int h = 0; h < 4; ++h) { c2[h].x *= rf0[h]; c2[h].y *= rf0[h]; }
#pragma unroll
      for (int h = 0; h < 4; ++h) { c2[4 + h].x *= rf1[h]; c2[4 + h].y *= rf1[h]; }
#pragma unroll
      for (int n = 0; n < 16; ++n) {
        const int cphys = (cslot0 + n) ^ cxor;
        const unsigned int nv = *(const unsigned int*)(&nf[cur][cphys * 8 + cj]);
        const float x0 = bf2f((unsigned short)(nv & 0xffffu));
        const float x1 = bf2f((unsigned short)(nv >> 16));
        const f32x4 p0 = *(const f32x4*)(&Pl[wid][n][0]);
        const f32x4 p1 = *(const f32x4*)(&Pl[wid][n][4]);
#pragma unroll
        for (int h = 0; h < 4; ++h) {
          c2[h].x = fmaf(p0[h], x0, c2[h].x);
          c2[h].y = fmaf(p0[h], x1, c2[h].y);
          c2[4 + h].x = fmaf(p1[h], x0, c2[4 + h].x);
          c2[4 + h].y = fmaf(p1[h], x1, c2[4 + h].y);
        }
      }
    }
  }

  // finalize
  if (r16 < NH && rg == 0) rfl[wid][r16] = 1.f / l;
  asm volatile("s_waitcnt lgkmcnt(0)" ::: "memory");
  {
    const f32x4 i0 = *(const f32x4*)(&rfl[wid][0]);
    const f32x4 i1 = *(const f32x4*)(&rfl[wid][4]);
    float* cb = ctx + (long)b * (NH * DD) + d0;
#pragma unroll
    for (int h = 0; h < 4; ++h) {
      cb[h * DD] = c2[h].x * i0[h];
      cb[h * DD + 1] = c2[h].y * i0[h];
      cb[(4 + h) * DD] = c2[4 + h].x * i1[h];
      cb[(4 + h) * DD + 1] = c2[4 + h].y * i1[h];
    }
  }
}

// ---- fused logits: MFMA dots from bf16 node + tanh/mask/log_softmax ----
__global__ __launch_bounds__(256) void logits_kernel(
    const unsigned short* __restrict__ nb16, const unsigned short* __restrict__ qk216,
    const int* __restrict__ mask, float* __restrict__ out)
{
  const int b = blockIdx.x;
  const int t = threadIdx.x;
  const int wid = t >> 6, lane = t & 63;
  const int r16 = lane & 15, rg = lane >> 4;
  __shared__ float sl[112];
  const unsigned short* qb = qk216 + (long)b * DD + rg * 8;

  for (int ti = wid; ti < 7; ti += 4) {
    const int arow = min(ti * 16 + r16, NNODE - 1);
    const unsigned short* ap = nb16 + ((long)b * NNODE + arow) * DD + rg * 8;
    f32x4 acc = {0.f, 0.f, 0.f, 0.f};
#pragma unroll
    for (int s = 0; s < 16; ++s) {
      const s16x8 av = *(const s16x8*)(ap + s * 32);
      const s16x8 bv = *(const s16x8*)(qb + s * 32);
      acc = __builtin_amdgcn_mfma_f32_16x16x32_bf16(av, bv, acc, 0, 0, 0);
    }
    if (r16 == 0) {
#pragma unroll
      for (int r = 0; r < 4; ++r) {
        const int n = ti * 16 + rg * 4 + r;
        if (n < 112) sl[n] = acc[r];
      }
    }
  }
  __syncthreads();
  if (t < 64) {
    float v0 = -3.0e38f, v1 = -3.0e38f;
    if (lane < NNODE)
      v0 = 10.f * tanhf(sl[lane]) - (float)mask[b * NNODE + lane] * 1e9f;
    if (lane + 64 < NNODE)
      v1 = 10.f * tanhf(sl[lane + 64]) - (float)mask[b * NNODE + lane + 64] * 1e9f;
    float mx = fmaxf(v0, v1);
#pragma unroll
    for (int off = 1; off < 64; off <<= 1) mx = fmaxf(mx, __shfl_xor(mx, off));
    float e = 0.f;
    if (lane < NNODE) e += __expf(v0 - mx);
    if (lane + 64 < NNODE) e += __expf(v1 - mx);
#pragma unroll
    for (int off = 1; off < 64; off <<= 1) e += __shfl_xor(e, off);
    const float lse = mx + __logf(e);
    float* ob = out + (long)b * NNODE;
    if (lane < NNODE) ob[lane] = v0 - lse;
    if (lane + 64 < NNODE) ob[lane + 64] = v1 - lse;
  }
}

extern "C" void kernel_launch(void* const* d_in, const int* in_sizes, int n_in,
                              void* d_out, int out_size, void* d_ws, size_t ws_size,
                              hipStream_t stream) {
  const float* node     = (const float*)d_in[0];
  const float* graph    = (const float*)d_in[1];
  const int*   tidx     = (const int*)d_in[2];
  const int*   mask     = (const int*)d_in[3];
  const float* W_target = (const float*)d_in[4];
  const float* W_global = (const float*)d_in[5];
  const float* W_K1     = (const float*)d_in[6];
  const float* W_K2     = (const float*)d_in[7];
  const float* W_Q      = (const float*)d_in[8];
  const float* W_V      = (const float*)d_in[9];
  const float* Wq_mha   = (const float*)d_in[10];
  const float* Wk_mha   = (const float*)d_in[11];
  const float* Wv_mha   = (const float*)d_in[12];
  const float* Wo_mha   = (const float*)d_in[13];
  float* out = (float*)d_out;

  float* base = (float*)d_ws;
  unsigned short* nb16 = (unsigned short*)base;          // 2048*100*512 bf16
  long off = 2048L * NNODE * DD / 2;                     // in floats
  float* A1 = base + off;        off += 262144;
  float* A2 = base + off;        off += 262144;
  float* Wkc = base + off;       off += 262144;
  float* Wvc = base + off;       off += 262144;
  float* Woq = base + off;       off += 262144;
  float* qbuf = base + off;      off += 2048L * 512;
  unsigned short* qk16 = (unsigned short*)(base + off);  off += 2048L * 4096 / 2;
  float* ctxb = base + off;      off += 2048L * 4096;
  float* preo = base + off;      off += 2048L * 512;
  float* query = base + off;     off += 2048L * 512;
  unsigned short* qk216 = (unsigned short*)(base + off); off += 2048L * 512 / 2;

  dim3 blk(256);
  const float SH = 0.125f;               // 1/sqrt(64)
  const float SD = 0.044194173824f;      // 1/sqrt(512)

  Fold5Args fa;
  fa.A[0] = Wq_mha;  fa.B[0] = W_target; fa.C[0] = A1;  fa.al[0] = 1.f;
  fa.A[1] = Wq_mha;  fa.B[1] = W_global; fa.C[1] = A2;  fa.al[1] = 1.f;
  fa.A[2] = Wk_mha;  fa.B[2] = W_K1;     fa.C[2] = Wkc; fa.al[2] = SH;
  fa.A[3] = Wv_mha;  fa.B[3] = W_V;      fa.C[3] = Wvc; fa.al[3] = 1.f;
  fa.A[4] = W_Q;     fa.B[4] = Wo_mha;   fa.C[4] = Woq; fa.al[4] = 1.f;
  fold5_kernel<<<dim3(8, 8, 5), blk, 0, stream>>>(fa);
  qbuf_kernel<<<dim3(8, 32), blk, 0, stream>>>(node, graph, tidx, A1, A2, qbuf);
  gemm_mfma<<<dim3(8, 32, 8), blk, 0, stream>>>(qbuf, Wkc, qk16,
      64, 512, 512, 4096, 64, 32768, 512, 0, 1.f, 0.f, 1);
  attn_fused<<<dim3(2048), dim3(256), 0, stream>>>(node, qk16, nb16, ctxb);
  gemm_mfma<<<dim3(1, 32, 8), blk, 0, stream>>>(ctxb, Wvc, preo,
      512, 4096, 512, 512, 512, 32768, 64, 1, 1.f, 0.f, 0);
  gemm_mfma<<<dim3(8, 32, 1), blk, 0, stream>>>(preo, Woq, query,
      512, 512, 512, 512, 0, 0, 0, 1, 1.f, 0.f, 0);
  gemm_mfma<<<dim3(8, 32, 1), blk, 0, stream>>>(query, W_K2, qk216,
      512, 512, 512, 512, 0, 0, 0, 0, SD, 0.f, 1);
  logits_kernel<<<dim3(2048), blk, 0, stream>>>(nb16, qk216, mask, out);

  (void)in_sizes; (void)n_in; (void)out_size; (void)ws_size;
}

// Round 6
// 300.667 us; speedup vs baseline: 2.4912x; 1.1269x over previous
//
#include <hip/hip_runtime.h>

#define DD 512
#define NNODE 100
#define NH 8

typedef __attribute__((ext_vector_type(4))) float f32x4;
typedef __attribute__((ext_vector_type(8))) short s16x8;

__device__ __forceinline__ unsigned short f2bf(float x) {
  union { float f; unsigned int u; } v; v.f = x;
  unsigned int r = v.u + 0x7fffu + ((v.u >> 16) & 1u);
  return (unsigned short)(r >> 16);
}
__device__ __forceinline__ float bf2f(unsigned short u) {
  union { unsigned int u; float f; } v; v.u = ((unsigned int)u) << 16;
  return v.f;
}

// ---- shared GEMM core: 64x64 tile, 4 waves, bf16 MFMA, 2-phase pipelined ----
struct StageRegs { float4 a4[2]; float as[8]; float4 b4[2]; float bs[8]; };

__device__ __forceinline__ void stage_issue(
    StageRegs& r, const float* __restrict__ A, const float* __restrict__ B,
    const int* __restrict__ gidx, int gmul, int k0, int lda, int ldb,
    int transA, int transB, int m0, int n0)
{
  const int t = threadIdx.x;
  const int tr = t >> 3, kq = t & 7;
  const int bn = t & 63, bk = t >> 6;
  if (!transA) {
#pragma unroll
    for (int rp = 0; rp < 2; ++rp) {
      const int gi = m0 + tr + rp * 32;
      long ab = (long)gi * lda;
      if (gidx) ab += (long)gidx[gi] * gmul;
      r.a4[rp] = *(const float4*)(A + ab + k0 + kq * 4);
    }
  } else {
#pragma unroll
    for (int pp = 0; pp < 8; ++pp)
      r.as[pp] = A[(long)(k0 + bk + pp * 4) * lda + m0 + bn];
  }
  if (transB) {
#pragma unroll
    for (int rp = 0; rp < 2; ++rp)
      r.b4[rp] = *(const float4*)(B + (long)(n0 + tr + rp * 32) * ldb + k0 + kq * 4);
  } else {
#pragma unroll
    for (int pp = 0; pp < 8; ++pp)
      r.bs[pp] = B[(long)(k0 + bk + pp * 4) * ldb + n0 + bn];
  }
}

__device__ __forceinline__ void stage_commit(
    const StageRegs& r, int transA, int transB,
    unsigned short (*As)[40], unsigned short (*Bs)[40])
{
  const int t = threadIdx.x;
  const int tr = t >> 3, kq = t & 7;
  const int bn = t & 63, bk = t >> 6;
  if (!transA) {
#pragma unroll
    for (int rp = 0; rp < 2; ++rp) {
      const float4 av = r.a4[rp];
      unsigned int p0 = (unsigned)f2bf(av.x) | ((unsigned)f2bf(av.y) << 16);
      unsigned int p1 = (unsigned)f2bf(av.z) | ((unsigned)f2bf(av.w) << 16);
      *(uint2*)(&As[tr + rp * 32][kq * 4]) = make_uint2(p0, p1);
    }
  } else {
#pragma unroll
    for (int pp = 0; pp < 8; ++pp) As[bn][bk + pp * 4] = f2bf(r.as[pp]);
  }
  if (transB) {
#pragma unroll
    for (int rp = 0; rp < 2; ++rp) {
      const float4 bv = r.b4[rp];
      unsigned int p0 = (unsigned)f2bf(bv.x) | ((unsigned)f2bf(bv.y) << 16);
      unsigned int p1 = (unsigned)f2bf(bv.z) | ((unsigned)f2bf(bv.w) << 16);
      *(uint2*)(&Bs[tr + rp * 32][kq * 4]) = make_uint2(p0, p1);
    }
  } else {
#pragma unroll
    for (int pp = 0; pp < 8; ++pp) Bs[bn][bk + pp * 4] = f2bf(r.bs[pp]);
  }
}

__device__ __forceinline__ void gemm_core(
    f32x4 acc[2][2], const float* __restrict__ A, const float* __restrict__ B,
    const int* __restrict__ gidx, int gmul, int K, int lda, int ldb,
    int transA, int transB, int m0, int n0,
    unsigned short (*As)[40], unsigned short (*Bs)[40])
{
  const int t = threadIdx.x;
  const int wid = t >> 6, lane = t & 63;
  const int wr = wid >> 1, wc = wid & 1;
  const int r16 = lane & 15, kg = (lane >> 4) * 8;
  StageRegs r;
  stage_issue(r, A, B, gidx, gmul, 0, lda, ldb, transA, transB, m0, n0);
  for (int k0 = 0; k0 < K; k0 += 32) {
    __syncthreads();                       // LDS free (prev tile consumed)
    stage_commit(r, transA, transB, As, Bs);
    __syncthreads();                       // LDS ready
    if (k0 + 32 < K)                       // issue AFTER barrier: stays in flight
      stage_issue(r, A, B, gidx, gmul, k0 + 32, lda, ldb, transA, transB, m0, n0);
    s16x8 a0 = *(const s16x8*)(&As[wr * 32 + r16][kg]);
    s16x8 a1 = *(const s16x8*)(&As[wr * 32 + 16 + r16][kg]);
    s16x8 b0 = *(const s16x8*)(&Bs[wc * 32 + r16][kg]);
    s16x8 b1 = *(const s16x8*)(&Bs[wc * 32 + 16 + r16][kg]);
    acc[0][0] = __builtin_amdgcn_mfma_f32_16x16x32_bf16(a0, b0, acc[0][0], 0, 0, 0);
    acc[0][1] = __builtin_amdgcn_mfma_f32_16x16x32_bf16(a0, b1, acc[0][1], 0, 0, 0);
    acc[1][0] = __builtin_amdgcn_mfma_f32_16x16x32_bf16(a1, b0, acc[1][0], 0, 0, 0);
    acc[1][1] = __builtin_amdgcn_mfma_f32_16x16x32_bf16(a1, b1, acc[1][1], 0, 0, 0);
  }
}

__device__ __forceinline__ void gemm_epilogue(
    f32x4 acc[2][2], void* Cv, int ldc, float alpha, float beta, int obf16,
    int m0, int n0)
{
  const int t = threadIdx.x;
  const int wid = t >> 6, lane = t & 63;
  const int wr = wid >> 1, wc = wid & 1;
  const int r16 = lane & 15;
#pragma unroll
  for (int si = 0; si < 2; ++si)
#pragma unroll
    for (int sj = 0; sj < 2; ++sj)
#pragma unroll
      for (int r = 0; r < 4; ++r) {
        const int row = m0 + wr * 32 + si * 16 + (lane >> 4) * 4 + r;
        const int col = n0 + wc * 32 + sj * 16 + r16;
        const long ci = (long)row * ldc + col;
        float v = alpha * acc[si][sj][r];
        if (obf16) {
          ((unsigned short*)Cv)[ci] = f2bf(v);
        } else {
          float* C = (float*)Cv;
          if (beta != 0.f) v = fmaf(beta, C[ci], v);
          C[ci] = v;
        }
      }
}

__global__ __launch_bounds__(256) void gemm_mfma(
    const float* __restrict__ A, const float* __restrict__ B, void* Cv,
    int K, int lda, int ldb, int ldc,
    long aoffz, long boffz, long coffz,
    int transA, int transB, float alpha, float beta, int obf16)
{
  __shared__ unsigned short As[64][40];
  __shared__ unsigned short Bs[64][40];
  A += (long)blockIdx.z * aoffz;
  B += (long)blockIdx.z * boffz;
  f32x4 acc[2][2] = {};
  gemm_core(acc, A, B, nullptr, 0, K, lda, ldb, transA, transB,
            blockIdx.y * 64, blockIdx.x * 64, As, Bs);
  void* Cz = obf16 ? (void*)((unsigned short*)Cv + (long)blockIdx.z * coffz)
                   : (void*)((float*)Cv + (long)blockIdx.z * coffz);
  gemm_epilogue(acc, Cz, ldc, alpha, beta, obf16, blockIdx.y * 64, blockIdx.x * 64);
}

struct Fold5Args {
  const float* A[5]; const float* B[5]; float* C[5]; float al[5]; int ta[5];
};

// 5 independent 512^3 weight folds (z selects); z may use transA
__global__ __launch_bounds__(256) void fold5_kernel(Fold5Args fa) {
  __shared__ unsigned short As[64][40];
  __shared__ unsigned short Bs[64][40];
  const int z = blockIdx.z;
  f32x4 acc[2][2] = {};
  gemm_core(acc, fa.A[z], fa.B[z], nullptr, 0, 512, 512, 512, fa.ta[z], 0,
            blockIdx.y * 64, blockIdx.x * 64, As, Bs);
  gemm_epilogue(acc, fa.C[z], 512, fa.al[z], 0.f, 0, blockIdx.y * 64, blockIdx.x * 64);
}

// by<32: qbuf = tgt@A1^T + graph@A2^T.  by>=32: M1 = Wo_mha^T @ T1.
__global__ __launch_bounds__(256) void qbufM1_kernel(
    const float* __restrict__ node, const float* __restrict__ graph,
    const int* __restrict__ tidx, const float* __restrict__ A1,
    const float* __restrict__ A2, float* __restrict__ qbuf,
    const float* __restrict__ Wo, const float* __restrict__ T1,
    float* __restrict__ M1)
{
  __shared__ unsigned short As[64][40];
  __shared__ unsigned short Bs[64][40];
  f32x4 acc[2][2] = {};
  const int n0 = blockIdx.x * 64;
  if (blockIdx.y < 32) {
    const int m0 = blockIdx.y * 64;
    gemm_core(acc, node, A1, tidx, DD, DD, NNODE * DD, DD, 0, 1, m0, n0, As, Bs);
    gemm_core(acc, graph, A2, nullptr, 0, DD, DD, DD, 0, 1, m0, n0, As, Bs);
    gemm_epilogue(acc, qbuf, DD, 1.f, 0.f, 0, m0, n0);
  } else {
    const int m0 = (blockIdx.y - 32) * 64;
    gemm_core(acc, Wo, T1, nullptr, 0, 512, 512, 512, 1, 0, m0, n0, As, Bs);
    gemm_epilogue(acc, M1, 512, 1.f, 0.f, 0, m0, n0);
  }
}

// ---- fused attention: single 16KB nf buffer + live prefetch + swizzle.
// One block per batch, 256 thr = 4 waves; ~27.3 KB LDS -> ~5 blocks/CU.
__global__ __launch_bounds__(256) void attn_fused(
    const float* __restrict__ node, const unsigned short* __restrict__ qk16,
    unsigned short* __restrict__ nb16, float* __restrict__ ctx)
{
  const int b = blockIdx.x;
  const int t = threadIdx.x;
  const int lane = t & 63;
  const int wid = t >> 6;
  const int r16 = lane & 15;
  const int rg = lane >> 4;

  __shared__ unsigned short nf[16 * 512];   // 16 KB, slot-swizzled
  __shared__ unsigned short qf[16 * 288];   // 9 KB
  __shared__ float Pl[4][16][8];
  __shared__ float rfl[4][8];

  {
    const unsigned short* qb = qk16 + (long)b * (NH * DD);
    for (int slot = t; slot < 512; slot += 256) {
      const int s = slot >> 5;
      const int idx = slot & 31;           // h*4+g
      const int h = idx >> 2, g = idx & 3;
      *(s16x8*)(&qf[s * 288 + idx * 8 + (idx >> 3) * 8]) =
          *(const s16x8*)(qb + h * DD + s * 32 + g * 8);
    }
  }

  const int r0 = t >> 7;
  const int c4 = (t * 4) & 511;
  const int slotbase = ((c4 >> 3) * 16) + r0;
  const int j_c = c4 & 7;
  const int d0 = t * 2;
  const int cslot0 = (d0 >> 3) * 16;
  const int cxor = (d0 >> 3) & 7;
  const int cj = d0 & 7;
  const int qidx = (r16 & 7) * 4 + rg;
  const int qfb = qidx * 8 + (qidx >> 3) * 8;

  const float* nbase = node + (long)b * (NNODE * DD);
  float4 rs[8];
  {
    const int lim = NNODE * DD;
#pragma unroll
    for (int i = 0; i < 8; ++i) {
      const int e = 4 * t + 1024 * i;
      rs[i] = (e < lim) ? *(const float4*)(nbase + e) : make_float4(0.f, 0.f, 0.f, 0.f);
    }
  }

  float m = -3.0e38f, l = 0.f;
  float2 c2[NH];
#pragma unroll
  for (int h = 0; h < NH; ++h) { c2[h].x = 0.f; c2[h].y = 0.f; }
  ushort4 h4s[8];

  for (int c = 0; c < 7; ++c) {
    const int c0 = c * 16;
    // cvt staged regs -> LDS (swizzled); keep bf16 in regs for global store
#pragma unroll
    for (int i = 0; i < 8; ++i) {
      ushort4 h4;
      h4.x = f2bf(rs[i].x); h4.y = f2bf(rs[i].y);
      h4.z = f2bf(rs[i].z); h4.w = f2bf(rs[i].w);
      h4s[i] = h4;
      const int slot = slotbase + 2 * i;
      const int phys = slot ^ ((slot >> 4) & 7);
      *(ushort4*)(&nf[phys * 8 + j_c]) = h4;
    }
    __syncthreads();                        // nf ready (qf too on c==0)
    // issue next-chunk loads AFTER the barrier: they stay in flight across
    // the whole compute phase and drain ~free at the end-of-body barrier
    if (c < 6) {
      const int nc0 = c0 + 16;
      const int lim = (NNODE - nc0) * DD;
#pragma unroll
      for (int i = 0; i < 8; ++i) {
        const int e = 4 * t + 1024 * i;
        rs[i] = (e < lim) ? *(const float4*)(nbase + (long)nc0 * DD + e)
                          : make_float4(0.f, 0.f, 0.f, 0.f);
      }
    }
#pragma unroll
    for (int i = 0; i < 8; ++i) {
      const int row = r0 + 2 * i;
      if (c0 + row < NNODE)
        *(ushort4*)(nb16 + ((long)b * NNODE + c0 + row) * DD + c4) = h4s[i];
    }

    // scores via MFMA (per-wave redundant; heads>=8 zero)
    f32x4 acc = {0.f, 0.f, 0.f, 0.f};
#pragma unroll
    for (int s = 0; s < 16; ++s) {
      const int slr = (s * 4 + rg) * 16 + r16;
      const s16x8 av = *(const s16x8*)(&nf[(slr ^ ((s * 4 + rg) & 7)) * 8]);
      s16x8 bv = {0, 0, 0, 0, 0, 0, 0, 0};
      if (r16 < NH) bv = *(const s16x8*)(&qf[s * 288 + qfb]);
      acc = __builtin_amdgcn_mfma_f32_16x16x32_bf16(av, bv, acc, 0, 0, 0);
    }
#pragma unroll
    for (int r = 0; r < 4; ++r)
      if (c0 + rg * 4 + r >= NNODE) acc[r] = -3.0e38f;

    // online softmax per head col r16 (reduce over rg via lane^16/^32)
    float cm = fmaxf(fmaxf(acc[0], acc[1]), fmaxf(acc[2], acc[3]));
    cm = fmaxf(cm, __shfl_xor(cm, 16));
    cm = fmaxf(cm, __shfl_xor(cm, 32));
    const float mn = fmaxf(m, cm);
    const float rf = __expf(m - mn);
    float p[4], ps = 0.f;
#pragma unroll
    for (int r = 0; r < 4; ++r) { p[r] = __expf(acc[r] - mn); ps += p[r]; }
    ps += __shfl_xor(ps, 16);
    ps += __shfl_xor(ps, 32);
    l = l * rf + ps;
    m = mn;
    if (r16 < NH) {
#pragma unroll
      for (int r = 0; r < 4; ++r) Pl[wid][rg * 4 + r][r16] = p[r];
      if (rg == 0) rfl[wid][r16] = rf;
    }
    asm volatile("s_waitcnt lgkmcnt(0)" ::: "memory");

    // ctx update (swizzled nv reads)
    {
      const f32x4 rf0 = *(const f32x4*)(&rfl[wid][0]);
      const f32x4 rf1 = *(const f32x4*)(&rfl[wid][4]);
#pragma unroll
      for (int h = 0; h < 4; ++h) { c2[h].x *= rf0[h]; c2[h].y *= rf0[h]; }
#pragma unroll
      for (int h = 0; h < 4; ++h) { c2[4 + h].x *= rf1[h]; c2[4 + h].y *= rf1[h]; }
#pragma unroll
      for (int n = 0; n < 16; ++n) {
        const int cphys = (cslot0 + n) ^ cxor;
        const unsigned int nv = *(const unsigned int*)(&nf[cphys * 8 + cj]);
        const float x0 = bf2f((unsigned short)(nv & 0xffffu));
        const float x1 = bf2f((unsigned short)(nv >> 16));
        const f32x4 p0 = *(const f32x4*)(&Pl[wid][n][0]);
        const f32x4 p1 = *(const f32x4*)(&Pl[wid][n][4]);
#pragma unroll
        for (int h = 0; h < 4; ++h) {
          c2[h].x = fmaf(p0[h], x0, c2[h].x);
          c2[h].y = fmaf(p0[h], x1, c2[h].y);
          c2[4 + h].x = fmaf(p1[h], x0, c2[4 + h].x);
          c2[4 + h].y = fmaf(p1[h], x1, c2[4 + h].y);
        }
      }
    }
    __syncthreads();                        // nf consumed -> next cvt may write
  }

  if (r16 < NH && rg == 0) rfl[wid][r16] = 1.f / l;
  asm volatile("s_waitcnt lgkmcnt(0)" ::: "memory");
  {
    const f32x4 i0 = *(const f32x4*)(&rfl[wid][0]);
    const f32x4 i1 = *(const f32x4*)(&rfl[wid][4]);
    float* cb = ctx + (long)b * (NH * DD) + d0;
#pragma unroll
    for (int h = 0; h < 4; ++h) {
      cb[h * DD] = c2[h].x * i0[h];
      cb[h * DD + 1] = c2[h].y * i0[h];
      cb[(4 + h) * DD] = c2[4 + h].x * i1[h];
      cb[(4 + h) * DD + 1] = c2[4 + h].y * i1[h];
    }
  }
}

// ---- fused logits: MFMA dots from bf16 node + tanh/mask/log_softmax ----
__global__ __launch_bounds__(256) void logits_kernel(
    const unsigned short* __restrict__ nb16, const unsigned short* __restrict__ qk216,
    const int* __restrict__ mask, float* __restrict__ out)
{
  const int b = blockIdx.x;
  const int t = threadIdx.x;
  const int wid = t >> 6, lane = t & 63;
  const int r16 = lane & 15, rg = lane >> 4;
  __shared__ float sl[112];
  const unsigned short* qb = qk216 + (long)b * DD + rg * 8;

  for (int ti = wid; ti < 7; ti += 4) {
    const int arow = min(ti * 16 + r16, NNODE - 1);
    const unsigned short* ap = nb16 + ((long)b * NNODE + arow) * DD + rg * 8;
    f32x4 acc = {0.f, 0.f, 0.f, 0.f};
#pragma unroll
    for (int s = 0; s < 16; ++s) {
      const s16x8 av = *(const s16x8*)(ap + s * 32);
      const s16x8 bv = *(const s16x8*)(qb + s * 32);
      acc = __builtin_amdgcn_mfma_f32_16x16x32_bf16(av, bv, acc, 0, 0, 0);
    }
    if (r16 == 0) {
#pragma unroll
      for (int r = 0; r < 4; ++r) {
        const int n = ti * 16 + rg * 4 + r;
        if (n < 112) sl[n] = acc[r];
      }
    }
  }
  __syncthreads();
  if (t < 64) {
    float v0 = -3.0e38f, v1 = -3.0e38f;
    if (lane < NNODE)
      v0 = 10.f * tanhf(sl[lane]) - (float)mask[b * NNODE + lane] * 1e9f;
    if (lane + 64 < NNODE)
      v1 = 10.f * tanhf(sl[lane + 64]) - (float)mask[b * NNODE + lane + 64] * 1e9f;
    float mx = fmaxf(v0, v1);
#pragma unroll
    for (int off = 1; off < 64; off <<= 1) mx = fmaxf(mx, __shfl_xor(mx, off));
    float e = 0.f;
    if (lane < NNODE) e += __expf(v0 - mx);
    if (lane + 64 < NNODE) e += __expf(v1 - mx);
#pragma unroll
    for (int off = 1; off < 64; off <<= 1) e += __shfl_xor(e, off);
    const float lse = mx + __logf(e);
    float* ob = out + (long)b * NNODE;
    if (lane < NNODE) ob[lane] = v0 - lse;
    if (lane + 64 < NNODE) ob[lane + 64] = v1 - lse;
  }
}

extern "C" void kernel_launch(void* const* d_in, const int* in_sizes, int n_in,
                              void* d_out, int out_size, void* d_ws, size_t ws_size,
                              hipStream_t stream) {
  const float* node     = (const float*)d_in[0];
  const float* graph    = (const float*)d_in[1];
  const int*   tidx     = (const int*)d_in[2];
  const int*   mask     = (const int*)d_in[3];
  const float* W_target = (const float*)d_in[4];
  const float* W_global = (const float*)d_in[5];
  const float* W_K1     = (const float*)d_in[6];
  const float* W_K2     = (const float*)d_in[7];
  const float* W_Q      = (const float*)d_in[8];
  const float* W_V      = (const float*)d_in[9];
  const float* Wq_mha   = (const float*)d_in[10];
  const float* Wk_mha   = (const float*)d_in[11];
  const float* Wv_mha   = (const float*)d_in[12];
  const float* Wo_mha   = (const float*)d_in[13];
  float* out = (float*)d_out;

  float* base = (float*)d_ws;
  unsigned short* nb16 = (unsigned short*)base;          // 2048*100*512 bf16
  long off = 2048L * NNODE * DD / 2;                     // in floats
  float* A1 = base + off;        off += 262144;
  float* A2 = base + off;        off += 262144;
  float* Wkc = base + off;       off += 262144;
  float* Wvc = base + off;       off += 262144;
  float* T1 = base + off;        off += 262144;
  float* M1 = base + off;        off += 262144;
  float* qbuf = base + off;      off += 2048L * 512;
  unsigned short* qk16 = (unsigned short*)(base + off);  off += 2048L * 4096 / 2;
  float* ctxb = base + off;      off += 2048L * 4096;
  float* preo = base + off;      off += 2048L * 512;
  unsigned short* qk216 = (unsigned short*)(base + off); off += 2048L * 512 / 2;

  dim3 blk(256);
  const float SH = 0.125f;               // 1/sqrt(64)
  const float SD = 0.044194173824f;      // 1/sqrt(512)

  // level-0 folds: A1=Wq@Wt, A2=Wq@Wg, Wkc=SH*(Wk@WK1), Wvc=Wv@WV, T1=W_Q^T@W_K2
  Fold5Args fa;
  fa.A[0] = Wq_mha;  fa.B[0] = W_target; fa.C[0] = A1;  fa.al[0] = 1.f; fa.ta[0] = 0;
  fa.A[1] = Wq_mha;  fa.B[1] = W_global; fa.C[1] = A2;  fa.al[1] = 1.f; fa.ta[1] = 0;
  fa.A[2] = Wk_mha;  fa.B[2] = W_K1;     fa.C[2] = Wkc; fa.al[2] = SH;  fa.ta[2] = 0;
  fa.A[3] = Wv_mha;  fa.B[3] = W_V;      fa.C[3] = Wvc; fa.al[3] = 1.f; fa.ta[3] = 0;
  fa.A[4] = W_Q;     fa.B[4] = W_K2;     fa.C[4] = T1;  fa.al[4] = 1.f; fa.ta[4] = 1;
  fold5_kernel<<<dim3(8, 8, 5), blk, 0, stream>>>(fa);
  // level-1: qbuf (by<32) and M1 = Wo_mha^T @ T1 (by>=32) in one launch
  qbufM1_kernel<<<dim3(8, 40), blk, 0, stream>>>(node, graph, tidx, A1, A2, qbuf,
                                                 Wo_mha, T1, M1);
  // qk16[b,h,:] = bf16( q[b, head h] @ Wkc[head h rows] )
  gemm_mfma<<<dim3(8, 32, 8), blk, 0, stream>>>(qbuf, Wkc, qk16,
      64, 512, 512, 4096, 64, 32768, 512, 0, 0, 1.f, 0.f, 1);
  // fused attention (node streamed once; bf16 cache written for logit pass)
  attn_fused<<<dim3(2048), blk, 0, stream>>>(node, qk16, nb16, ctxb);
  // preo[b, head h] = ctx[b,h,:] @ Wvc[head h rows]^T
  gemm_mfma<<<dim3(1, 32, 8), blk, 0, stream>>>(ctxb, Wvc, preo,
      512, 4096, 512, 512, 512, 32768, 64, 0, 1, 1.f, 0.f, 0);
  // qk2 = bf16( SD * preo @ M1 )   (replaces query+qk216 chain)
  gemm_mfma<<<dim3(8, 32, 1), blk, 0, stream>>>(preo, M1, qk216,
      512, 512, 512, 512, 0, 0, 0, 0, 0, SD, 0.f, 1);
  // fused logit pass
  logits_kernel<<<dim3(2048), blk, 0, stream>>>(nb16, qk216, mask, out);

  (void)in_sizes; (void)n_in; (void)out_size; (void)ws_size;
}